// Round 7
// baseline (678.676 us; speedup 1.0000x reference)
//
#include <hip/hip_runtime.h>
#include <math.h>

#define NN 10000
#define NE 160000
#define HCW 512
#define CH 128
#define NLAYERS 4
#define LN_EPS 1e-5f
#define NBUCK 128   // LN-stat atomic buckets, each on its own 64B line

typedef short bf16x8 __attribute__((ext_vector_type(8)));
typedef float f32x4 __attribute__((ext_vector_type(4)));

__device__ inline unsigned short f2bf(float f) {
    union { float f; unsigned int u; } x; x.f = f;
    unsigned int u = x.u;
    return (unsigned short)((u + 0x7FFFu + ((u >> 16) & 1u)) >> 16);
}
__device__ inline float bf2f(unsigned short s) {
    union { unsigned int u; float f; } x; x.u = ((unsigned int)s) << 16;
    return x.f;
}
__device__ inline float lo16(unsigned int u) {
    union { unsigned int x; float f; } v; v.x = u << 16; return v.f;
}
__device__ inline float hi16(unsigned int u) {
    union { unsigned int x; float f; } v; v.x = u & 0xffff0000u; return v.f;
}

// DPP row_ror add within 16-lane rows
template<int CTRL>
__device__ inline float dppadd(float x) {
    int y = __builtin_amdgcn_update_dpp(0, __float_as_int(x), CTRL, 0xF, 0xF, true);
    return x + __int_as_float(y);
}
__device__ inline float red16(float x) {
    x = dppadd<0x128>(x);  // row_ror:8
    x = dppadd<0x124>(x);  // row_ror:4
    x = dppadd<0x122>(x);  // row_ror:2
    x = dppadd<0x121>(x);  // row_ror:1
    return x;
}
__device__ inline float red64(float x) {
    x = red16(x);
    x += __shfl_xor(x, 16, 64);
    x += __shfl_xor(x, 32, 64);
    return x;
}

__device__ inline float dot8(const float4& q0, const float4& q1, const uint4& kk) {
    return q0.x * lo16(kk.x) + q0.y * hi16(kk.x)
         + q0.z * lo16(kk.y) + q0.w * hi16(kk.y)
         + q1.x * lo16(kk.z) + q1.y * hi16(kk.z)
         + q1.z * lo16(kk.w) + q1.w * hi16(kk.w);
}

// ---------------- CSR build ----------------
__global__ void k_init(int* cnt, int* fill, float* stats) {
    int i = blockIdx.x * blockDim.x + threadIdx.x;
    if (i < NN) { cnt[i] = 0; fill[i] = 0; }
    if (i < NLAYERS * NBUCK * 16) stats[i] = 0.f;
}

__global__ void k_count(const int* __restrict__ dst, int* __restrict__ cnt) {
    int e = blockIdx.x * blockDim.x + threadIdx.x;
    if (e < NE) atomicAdd(&cnt[dst[e]], 1);
}

__global__ __launch_bounds__(1024) void k_scan(const int* __restrict__ cnt, int* __restrict__ offs) {
    __shared__ int sh[1024];
    __shared__ int carry;
    if (threadIdx.x == 0) carry = 0;
    __syncthreads();
    for (int base = 0; base < NN; base += 1024) {
        int i = base + threadIdx.x;
        int v = (i < NN) ? cnt[i] : 0;
        sh[threadIdx.x] = v;
        __syncthreads();
        for (int off = 1; off < 1024; off <<= 1) {
            int t = (threadIdx.x >= off) ? sh[threadIdx.x - off] : 0;
            __syncthreads();
            sh[threadIdx.x] += t;
            __syncthreads();
        }
        int incl = sh[threadIdx.x];
        if (i < NN) offs[i] = carry + incl - v;
        __syncthreads();
        if (threadIdx.x == 1023) carry += sh[1023];
        __syncthreads();
    }
    if (threadIdx.x == 0) offs[NN] = carry;
}

__global__ void k_fill(const int* __restrict__ src, const int* __restrict__ dst,
                       const int* __restrict__ offs, int* __restrict__ fill,
                       int* __restrict__ col) {
    int e = blockIdx.x * blockDim.x + threadIdx.x;
    if (e < NE) {
        int d = dst[e];
        int p = offs[d] + atomicAdd(&fill[d], 1);
        col[p] = src[e];
    }
}

// ---------------- weight convert: fp32 -> bf16, [K][N] -> [N][K] ----------------
__global__ void k_wconv(const float* __restrict__ Wq, const float* __restrict__ Wk,
                        const float* __restrict__ Wv, const float* __restrict__ Ws,
                        const float* __restrict__ Wp,
                        unsigned short* __restrict__ wt_qkvs,   // [L][2048][128]
                        unsigned short* __restrict__ wpt) {     // [L][128][512]
    int id = blockIdx.x * blockDim.x + threadIdx.x;
    if (id < NLAYERS * 2048 * 128) {
        int l = id >> 18;
        int rem = id & 262143;
        int n = rem >> 7, k = rem & 127;
        int mat = n >> 9, wcol = n & 511;
        const float* W = (mat == 0) ? Wq : (mat == 1) ? Wk : (mat == 2) ? Wv : Ws;
        wt_qkvs[id] = f2bf(W[(size_t)l * 65536 + k * 512 + wcol]);
    } else if (id < NLAYERS * 2048 * 128 + NLAYERS * 128 * 512) {
        int id2 = id - NLAYERS * 2048 * 128;
        int l = id2 >> 16;
        int rem = id2 & 65535;
        int n = rem >> 9, k = rem & 511;
        wpt[(size_t)l * 65536 + n * 512 + k] = f2bf(Wp[(size_t)l * 65536 + k * 128 + n]);
    }
}

// ---------------- input projection ----------------
__global__ __launch_bounds__(128) void k_inproj(const float* __restrict__ x,
                                                const float* __restrict__ W,
                                                const float* __restrict__ b,
                                                float* __restrict__ h,
                                                unsigned short* __restrict__ h_bf) {
    int n = blockIdx.x;
    int j = threadIdx.x;
    float acc = b[j];
#pragma unroll
    for (int i = 0; i < 15; i++) acc += x[n * 15 + i] * W[i * 128 + j];
    h[n * 128 + j] = acc;
    h_bf[n * 128 + j] = f2bf(acc);
}

// ---------------- fused qkv+skip MFMA GEMM ----------------
// grid (79, 8): y*256 .. y*256+255 output cols, 2 subtiles of 128.
// A-tile staged once, fragments hoisted to registers. All outputs bf16:
// q -> qb16[N][512], k -> kv16[N][0..511], v -> kv16[N][512..1023], skip -> sb16.
__global__ __launch_bounds__(256) void k_qkvs_mfma(
    const unsigned short* __restrict__ h_bf,   // [NN][128]
    const unsigned short* __restrict__ Wt,     // [2048][128] layer slice
    const float* __restrict__ bq, const float* __restrict__ bk,
    const float* __restrict__ bv, const float* __restrict__ bs,
    unsigned short* __restrict__ qb16, unsigned short* __restrict__ kv16,
    unsigned short* __restrict__ sb16) {
    __shared__ unsigned short As[128 * 128];
    __shared__ unsigned short Bs[128 * 128];
    int row0 = blockIdx.x * 128;
    int t = threadIdx.x;
    // stage A once
#pragma unroll
    for (int i = 0; i < 8; i++) {
        int c = t + i * 256;
        int r = c >> 4, cc = c & 15;
        int gr = row0 + r;
        uint4 v = make_uint4(0, 0, 0, 0);
        if (gr < NN) v = *(const uint4*)(h_bf + (size_t)gr * 128 + cc * 8);
        int sc = (r << 4) | (cc ^ (r & 7));
        *(uint4*)(As + sc * 8) = v;
    }
    int wave = t >> 6, lane = t & 63;
    int wr = (wave >> 1) * 64, wc = (wave & 1) * 64;
    int lr = lane & 15, lk = lane >> 4;
    bf16x8 afr[16];   // [ks*4+mi]
    for (int sub = 0; sub < 2; sub++) {
        int n0 = blockIdx.y * 256 + sub * 128;   // global output col base
        __syncthreads();   // A ready (sub 0) / prior B reads done (sub 1)
#pragma unroll
        for (int i = 0; i < 8; i++) {
            int c = t + i * 256;
            int r = c >> 4, cc = c & 15;
            uint4 v = *(const uint4*)(Wt + (size_t)(n0 + r) * 128 + cc * 8);
            int sc = (r << 4) | (cc ^ (r & 7));
            *(uint4*)(Bs + sc * 8) = v;
        }
        if (sub == 0) {
#pragma unroll
            for (int ks = 0; ks < 4; ks++)
#pragma unroll
                for (int mi = 0; mi < 4; mi++) {
                    int r = wr + mi * 16 + lr;
                    int cc = (ks * 4 + lk) ^ (r & 7);
                    afr[ks * 4 + mi] = *(const bf16x8*)(As + (((r << 4) | cc) * 8));
                }
        }
        __syncthreads();
        f32x4 acc[4][4] = {};
#pragma unroll
        for (int ks = 0; ks < 4; ks++) {
            bf16x8 b[4];
#pragma unroll
            for (int ni = 0; ni < 4; ni++) {
                int r = wc + ni * 16 + lr;
                int cc = (ks * 4 + lk) ^ (r & 7);
                b[ni] = *(const bf16x8*)(Bs + (((r << 4) | cc) * 8));
            }
#pragma unroll
            for (int mi = 0; mi < 4; mi++)
#pragma unroll
                for (int ni = 0; ni < 4; ni++)
                    acc[mi][ni] = __builtin_amdgcn_mfma_f32_16x16x32_bf16(afr[ks * 4 + mi], b[ni], acc[mi][ni], 0, 0, 0);
        }
#pragma unroll
        for (int ni = 0; ni < 4; ni++) {
            int gc = n0 + wc + ni * 16 + lr;
            int mat = gc >> 9, wcol = gc & 511;
            float bias = ((mat == 0) ? bq : (mat == 1) ? bk : (mat == 2) ? bv : bs)[wcol];
#pragma unroll
            for (int mi = 0; mi < 4; mi++) {
                int gr0 = row0 + wr + mi * 16 + 4 * lk;
#pragma unroll
                for (int r = 0; r < 4; r++) {
                    int grr = gr0 + r;
                    if (grr < NN) {
                        unsigned short val = f2bf(acc[mi][ni][r] + bias);
                        if (mat == 0)      qb16[(size_t)grr * 512 + wcol] = val;
                        else if (mat == 1) kv16[((size_t)grr << 10) + wcol] = val;
                        else if (mat == 2) kv16[((size_t)grr << 10) + 512 + wcol] = val;
                        else               sb16[(size_t)grr * 512 + wcol] = val;
                    }
                }
            }
        }
    }
}

// ---------------- fused attention + beta gate + LN stats ----------------
// one block per node, one wave per head; 4 groups of 16 lanes, 2 ILP states
// per group (8 edges in flight/wave). q/skip/gated bf16. DPP reduces.
__global__ __launch_bounds__(256) void k_attn_beta(
    const unsigned short* __restrict__ qb16,
    const unsigned short* __restrict__ kv16,
    const unsigned short* __restrict__ sb16,
    const float* __restrict__ Wb,
    const int* __restrict__ offs, const int* __restrict__ col,
    unsigned short* __restrict__ gated16, float* __restrict__ stats) {
    int n = blockIdx.x;
    int head = threadIdx.x >> 6;
    int lane = threadIdx.x & 63;
    int g = lane >> 4;         // edge group 0..3
    int subl = lane & 15;      // 8 channels per lane
    const int hbase = head * CH;
    const int off = hbase + subl * 8;
    uint4 qq = *(const uint4*)(qb16 + (size_t)n * HCW + off);
    float4 q0 = {lo16(qq.x), hi16(qq.x), lo16(qq.y), hi16(qq.y)};
    float4 q1 = {lo16(qq.z), hi16(qq.z), lo16(qq.w), hi16(qq.w)};
    int beg = offs[n], end = offs[n + 1];
    const float scale = 0.08838834764831845f;  // 1/sqrt(128)

    float mA = -INFINITY, sA = 0.f, mB = -INFINITY, sB = 0.f;
    float4 a0A = {0.f, 0.f, 0.f, 0.f}, a1A = {0.f, 0.f, 0.f, 0.f};
    float4 a0B = {0.f, 0.f, 0.f, 0.f}, a1B = {0.f, 0.f, 0.f, 0.f};

    for (int p = beg + g; p < end; p += 8) {
        int pB = p + 4;
        bool hasB = (pB < end);
        int snA = col[p];
        int snB = hasB ? col[pB] : snA;
        const unsigned short* bA = kv16 + ((size_t)snA << 10) + off;
        const unsigned short* bB = kv16 + ((size_t)snB << 10) + off;
        uint4 kkA = *(const uint4*)bA;
        uint4 vvA = *(const uint4*)(bA + 512);
        uint4 kkB = *(const uint4*)bB;
        uint4 vvB = *(const uint4*)(bB + 512);
        float dA = dot8(q0, q1, kkA);
        float dB = dot8(q0, q1, kkB);
        dA = red16(dA);
        dB = red16(dB);
        float lA = dA * scale;
        float lB = dB * scale;
        if (lA <= mA + 8.f) {             // fast path: no rescale
            float w = __expf(lA - mA);
            sA += w;
            a0A.x += w * lo16(vvA.x); a0A.y += w * hi16(vvA.x);
            a0A.z += w * lo16(vvA.y); a0A.w += w * hi16(vvA.y);
            a1A.x += w * lo16(vvA.z); a1A.y += w * hi16(vvA.z);
            a1A.z += w * lo16(vvA.w); a1A.w += w * hi16(vvA.w);
        } else {                          // rescale (first edge & rare growth)
            float sc = __expf(mA - lA);   // mA=-inf -> 0
            sA = sA * sc + 1.f;
            a0A.x = a0A.x * sc + lo16(vvA.x); a0A.y = a0A.y * sc + hi16(vvA.x);
            a0A.z = a0A.z * sc + lo16(vvA.y); a0A.w = a0A.w * sc + hi16(vvA.y);
            a1A.x = a1A.x * sc + lo16(vvA.z); a1A.y = a1A.y * sc + hi16(vvA.z);
            a1A.z = a1A.z * sc + lo16(vvA.w); a1A.w = a1A.w * sc + hi16(vvA.w);
            mA = lA;
        }
        if (hasB) {
            if (lB <= mB + 8.f) {
                float w = __expf(lB - mB);
                sB += w;
                a0B.x += w * lo16(vvB.x); a0B.y += w * hi16(vvB.x);
                a0B.z += w * lo16(vvB.y); a0B.w += w * hi16(vvB.y);
                a1B.x += w * lo16(vvB.z); a1B.y += w * hi16(vvB.z);
                a1B.z += w * lo16(vvB.w); a1B.w += w * hi16(vvB.w);
            } else {
                float sc = __expf(mB - lB);
                sB = sB * sc + 1.f;
                a0B.x = a0B.x * sc + lo16(vvB.x); a0B.y = a0B.y * sc + hi16(vvB.x);
                a0B.z = a0B.z * sc + lo16(vvB.y); a0B.w = a0B.w * sc + hi16(vvB.y);
                a1B.x = a1B.x * sc + lo16(vvB.z); a1B.y = a1B.y * sc + hi16(vvB.z);
                a1B.z = a1B.z * sc + lo16(vvB.w); a1B.w = a1B.w * sc + hi16(vvB.w);
                mB = lB;
            }
        }
    }
    // merge B into A (per-lane)
    {
        float mn = fmaxf(mA, mB);
        float c1 = (sA > 0.f) ? __expf(mA - mn) : 0.f;
        float c2 = (sB > 0.f) ? __expf(mB - mn) : 0.f;
        sA = sA * c1 + sB * c2;
        a0A.x = a0A.x * c1 + a0B.x * c2; a0A.y = a0A.y * c1 + a0B.y * c2;
        a0A.z = a0A.z * c1 + a0B.z * c2; a0A.w = a0A.w * c1 + a0B.w * c2;
        a1A.x = a1A.x * c1 + a1B.x * c2; a1A.y = a1A.y * c1 + a1B.y * c2;
        a1A.z = a1A.z * c1 + a1B.z * c2; a1A.w = a1A.w * c1 + a1B.w * c2;
        mA = mn;
    }
    // merge the 4 group states (lane^16, lane^32 hold same channels)
#pragma unroll
    for (int off2 = 16; off2 <= 32; off2 <<= 1) {
        float m_o = __shfl_xor(mA, off2, 64);
        float s_o = __shfl_xor(sA, off2, 64);
        float4 b0, b1;
        b0.x = __shfl_xor(a0A.x, off2, 64); b0.y = __shfl_xor(a0A.y, off2, 64);
        b0.z = __shfl_xor(a0A.z, off2, 64); b0.w = __shfl_xor(a0A.w, off2, 64);
        b1.x = __shfl_xor(a1A.x, off2, 64); b1.y = __shfl_xor(a1A.y, off2, 64);
        b1.z = __shfl_xor(a1A.z, off2, 64); b1.w = __shfl_xor(a1A.w, off2, 64);
        float mn = fmaxf(mA, m_o);
        float c1 = (sA > 0.f) ? __expf(mA - mn) : 0.f;
        float c2 = (s_o > 0.f) ? __expf(m_o - mn) : 0.f;
        sA = sA * c1 + s_o * c2;
        a0A.x = a0A.x * c1 + b0.x * c2; a0A.y = a0A.y * c1 + b0.y * c2;
        a0A.z = a0A.z * c1 + b0.z * c2; a0A.w = a0A.w * c1 + b0.w * c2;
        a1A.x = a1A.x * c1 + b1.x * c2; a1A.y = a1A.y * c1 + b1.y * c2;
        a1A.z = a1A.z * c1 + b1.z * c2; a1A.w = a1A.w * c1 + b1.w * c2;
        mA = mn;
    }
    float inv = (sA > 0.f) ? 1.f / sA : 0.f;

    __shared__ float att_s[512];
    if (g == 0) {
        float4 o0 = {a0A.x * inv, a0A.y * inv, a0A.z * inv, a0A.w * inv};
        float4 o1 = {a1A.x * inv, a1A.y * inv, a1A.z * inv, a1A.w * inv};
        *(float4*)(att_s + off) = o0;
        *(float4*)(att_s + off + 4) = o1;
    }
    __syncthreads();

    // beta gate: channels c0 = head*128 + 2*lane, c1 = c0+1
    int c0 = hbase + lane * 2;
    float o0 = att_s[c0], o1 = att_s[c0 + 1];
    unsigned int sku = *(const unsigned int*)(sb16 + (size_t)n * HCW + c0);
    float skx = lo16(sku), sky = hi16(sku);
    float part = o0 * Wb[c0] + o1 * Wb[c0 + 1]
               + skx * Wb[512 + c0] + sky * Wb[512 + c0 + 1]
               + (o0 - skx) * Wb[1024 + c0] + (o1 - sky) * Wb[1024 + c0 + 1];
    part = red64(part);
    __shared__ float red[4];
    if (lane == 0) red[head] = part;
    __syncthreads();
    float tot = red[0] + red[1] + red[2] + red[3];
    float beta = 1.f / (1.f + __expf(-tot));
    float gx = beta * skx + (1.f - beta) * o0;
    float gy = beta * sky + (1.f - beta) * o1;
    unsigned int gu = (unsigned int)f2bf(gx) | ((unsigned int)f2bf(gy) << 16);
    *(unsigned int*)(gated16 + (size_t)n * HCW + c0) = gu;

    // LN partial sums on the rounded (stored) values -> bucketed atomics
    float gxr = lo16(gu), gyr = hi16(gu);
    float ls = red64(gxr + gyr);
    float lq = red64(gxr * gxr + gyr * gyr);
    __shared__ float r2[8];
    if (lane == 0) { r2[head] = ls; r2[4 + head] = lq; }
    __syncthreads();
    if (threadIdx.x == 0) {
        int b = n & (NBUCK - 1);
        atomicAdd(&stats[b * 16], r2[0] + r2[1] + r2[2] + r2[3]);
        atomicAdd(&stats[b * 16 + 1], r2[4] + r2[5] + r2[6] + r2[7]);
    }
}

// ---------------- LN + proj MFMA + residual + relu ----------------
// 64-row tiles, 8 waves (512 thr): wave w computes 16 rows x 64 cols.
__global__ __launch_bounds__(512) void k_proj_mfma(
    const unsigned short* __restrict__ gated16,   // [NN][512] bf16
    const unsigned short* __restrict__ Wpt,       // [128][512] layer slice
    const float* __restrict__ bp,
    const float* __restrict__ lw, const float* __restrict__ lb,
    const float* __restrict__ stats,
    float* __restrict__ h, unsigned short* __restrict__ h_bf) {
    __shared__ unsigned short As[64 * 128];    // 16KB
    __shared__ unsigned short Bs[128 * 128];   // 32KB
    int row0 = blockIdx.x * 64;
    int t = threadIdx.x;
    float ssum = 0.f, sq = 0.f;
#pragma unroll 16
    for (int i = 0; i < NBUCK; i++) { ssum += stats[i * 16]; sq += stats[i * 16 + 1]; }
    const float invM = 1.f / (NN * 512.f);
    float mean = ssum * invM;
    float ms = sq * invM - mean * mean;
    float rstd = 1.f / (sqrtf(fmaxf(ms, 0.f)) + LN_EPS);
    int wave = t >> 6, lane = t & 63;
    int wr = (wave >> 1) * 16, wc = (wave & 1) * 64;
    int lr = lane & 15, lk = lane >> 4;
    f32x4 acc[4] = {};
    for (int kc = 0; kc < 4; kc++) {
        __syncthreads();
#pragma unroll
        for (int i = 0; i < 2; i++) {
            int c = t + i * 512;
            int r = c >> 4, cc = c & 15;
            int gr = row0 + r;
            int gk = kc * 128 + cc * 8;
            unsigned short u[8];
            if (gr < NN) {
                uint4 gv = *(const uint4*)(gated16 + (size_t)gr * 512 + gk);
                float vals[8] = {lo16(gv.x), hi16(gv.x), lo16(gv.y), hi16(gv.y),
                                 lo16(gv.z), hi16(gv.z), lo16(gv.w), hi16(gv.w)};
#pragma unroll
                for (int j = 0; j < 8; j++)
                    u[j] = f2bf((vals[j] - mean) * rstd * lw[gk + j] + lb[gk + j]);
            } else {
#pragma unroll
                for (int j = 0; j < 8; j++) u[j] = 0;
            }
            int sc = (r << 4) | (cc ^ (r & 7));
            *(uint4*)(As + sc * 8) = *(uint4*)u;
        }
#pragma unroll
        for (int i = 0; i < 4; i++) {
            int c = t + i * 512;
            int r = c >> 4, cc = c & 15;
            uint4 v = *(const uint4*)(Wpt + (size_t)r * 512 + kc * 128 + cc * 8);
            int sc = (r << 4) | (cc ^ (r & 7));
            *(uint4*)(Bs + sc * 8) = v;
        }
        __syncthreads();
#pragma unroll
        for (int ks = 0; ks < 4; ks++) {
            bf16x8 a, b[4];
            {
                int r = wr + lr;
                int cc = (ks * 4 + lk) ^ (r & 7);
                a = *(const bf16x8*)(As + (((r << 4) | cc) * 8));
            }
#pragma unroll
            for (int ni = 0; ni < 4; ni++) {
                int r = wc + ni * 16 + lr;
                int cc = (ks * 4 + lk) ^ (r & 7);
                b[ni] = *(const bf16x8*)(Bs + (((r << 4) | cc) * 8));
            }
#pragma unroll
            for (int ni = 0; ni < 4; ni++)
                acc[ni] = __builtin_amdgcn_mfma_f32_16x16x32_bf16(a, b[ni], acc[ni], 0, 0, 0);
        }
    }
#pragma unroll
    for (int ni = 0; ni < 4; ni++) {
        int gc = wc + ni * 16 + lr;  // 0..127
        float bias = bp[gc];
        int gr0 = row0 + wr + 4 * lk;
#pragma unroll
        for (int r = 0; r < 4; r++) {
            int grr = gr0 + r;
            if (grr < NN) {
                float o = acc[ni][r] + bias + h[(size_t)grr * 128 + gc];
                o = fmaxf(o, 0.f);
                h[(size_t)grr * 128 + gc] = o;
                h_bf[(size_t)grr * 128 + gc] = f2bf(o);
            }
        }
    }
}

// ---------------- output projection ----------------
__global__ void k_out(const float* __restrict__ h, const float* __restrict__ W,
                      const float* __restrict__ b, float* __restrict__ out) {
    int i = blockIdx.x * blockDim.x + threadIdx.x;
    if (i >= NN * 5) return;
    int n = i / 5, j = i % 5;
    float acc = b[j];
    for (int k = 0; k < 128; k++) acc += h[(size_t)n * 128 + k] * W[k * 5 + j];
    out[i] = acc;
}

extern "C" void kernel_launch(void* const* d_in, const int* in_sizes, int n_in,
                              void* d_out, int out_size, void* d_ws, size_t ws_size,
                              hipStream_t stream) {
    const float* x     = (const float*)d_in[0];
    const int* ei      = (const int*)d_in[1];
    const float* W_in  = (const float*)d_in[2];
    const float* b_in  = (const float*)d_in[3];
    const float* W_out = (const float*)d_in[4];
    const float* b_out = (const float*)d_in[5];
    const float* Wq    = (const float*)d_in[6];
    const float* bq    = (const float*)d_in[7];
    const float* Wk    = (const float*)d_in[8];
    const float* bk    = (const float*)d_in[9];
    const float* Wv    = (const float*)d_in[10];
    const float* bv    = (const float*)d_in[11];
    const float* Wsk   = (const float*)d_in[12];
    const float* bsk   = (const float*)d_in[13];
    const float* Wbeta = (const float*)d_in[14];
    const float* ln_w  = (const float*)d_in[15];
    const float* ln_b  = (const float*)d_in[16];
    const float* Wproj = (const float*)d_in[17];
    const float* bproj = (const float*)d_in[18];
    float* out = (float*)d_out;

    // workspace layout
    float* h     = (float*)d_ws;                    // N*128 f32
    float* stats = h + (size_t)NN * 128;            // L*NBUCK*16
    int* offs = (int*)(stats + NLAYERS * NBUCK * 16);  // N+1
    int* cnt  = offs + (NN + 1);
    int* fill = cnt + NN;
    int* col  = fill + NN;                          // E
    unsigned short* h_bf = (unsigned short*)(((uintptr_t)(col + NE) + 15) & ~(uintptr_t)15);
    unsigned short* qb16 = h_bf + (size_t)NN * 128;                // N*512 (also gated)
    unsigned short* sb16 = qb16 + (size_t)NN * 512;                // N*512
    unsigned short* kv16 = sb16 + (size_t)NN * 512;                // N*1024 interleaved K|V
    unsigned short* wt_qkvs = kv16 + (size_t)NN * 1024;            // L*2048*128
    unsigned short* wpt = wt_qkvs + (size_t)NLAYERS * 2048 * 128;  // L*128*512
    unsigned short* gated16 = qb16;  // alias (block n reads q row n before writing)

    const int* src = ei;
    const int* dst = ei + NE;

    k_init<<<(NN + 255) / 256, 256, 0, stream>>>(cnt, fill, stats);
    k_count<<<(NE + 255) / 256, 256, 0, stream>>>(dst, cnt);
    k_scan<<<1, 1024, 0, stream>>>(cnt, offs);
    k_fill<<<(NE + 255) / 256, 256, 0, stream>>>(src, dst, offs, fill, col);
    {
        int tot = NLAYERS * 2048 * 128 + NLAYERS * 128 * 512;
        k_wconv<<<(tot + 255) / 256, 256, 0, stream>>>(Wq, Wk, Wv, Wsk, Wproj, wt_qkvs, wpt);
    }
    k_inproj<<<NN, 128, 0, stream>>>(x, W_in, b_in, h, h_bf);

    for (int l = 0; l < NLAYERS; ++l) {
        const unsigned short* Wt_ = wt_qkvs + (size_t)l * 2048 * 128;
        const unsigned short* Wp_ = wpt + (size_t)l * 128 * 512;
        const float* bq_ = bq + l * 512;
        const float* bk_ = bk + l * 512;
        const float* bv_ = bv + l * 512;
        const float* bs_ = bsk + l * 512;
        const float* Wb_ = Wbeta + (size_t)l * 1536;
        const float* lw_ = ln_w + l * 512;
        const float* lb_ = ln_b + l * 512;
        const float* bp_ = bproj + l * 128;
        float* st = stats + (size_t)l * NBUCK * 16;

        dim3 g1((NN + 127) / 128, 8);
        k_qkvs_mfma<<<g1, 256, 0, stream>>>(h_bf, Wt_, bq_, bk_, bv_, bs_,
                                            qb16, kv16, sb16);
        k_attn_beta<<<NN, 256, 0, stream>>>(qb16, kv16, sb16, Wb_, offs, col, gated16, st);
        k_proj_mfma<<<(NN + 63) / 64, 512, 0, stream>>>(gated16, Wp_, bp_, lw_, lb_, st, h, h_bf);
    }
    k_out<<<(NN * 5 + 255) / 256, 256, 0, stream>>>(h, W_out, b_out, out);
}

// Round 8
// 453.028 us; speedup vs baseline: 1.4981x; 1.4981x over previous
//
#include <hip/hip_runtime.h>
#include <math.h>

#define NN 10000
#define NE 160000
#define HCW 512
#define CH 128
#define NLAYERS 4
#define LN_EPS 1e-5f
#define NBUCK 128   // LN-stat atomic buckets, each on its own 64B line

typedef short bf16x8 __attribute__((ext_vector_type(8)));
typedef float f32x4 __attribute__((ext_vector_type(4)));

__device__ inline unsigned short f2bf(float f) {
    union { float f; unsigned int u; } x; x.f = f;
    unsigned int u = x.u;
    return (unsigned short)((u + 0x7FFFu + ((u >> 16) & 1u)) >> 16);
}
__device__ inline float bf2f(unsigned short s) {
    union { unsigned int u; float f; } x; x.u = ((unsigned int)s) << 16;
    return x.f;
}
__device__ inline float lo16(unsigned int u) {
    union { unsigned int x; float f; } v; v.x = u << 16; return v.f;
}
__device__ inline float hi16(unsigned int u) {
    union { unsigned int x; float f; } v; v.x = u & 0xffff0000u; return v.f;
}

// DPP row_ror add within 16-lane rows
template<int CTRL>
__device__ inline float dppadd(float x) {
    int y = __builtin_amdgcn_update_dpp(0, __float_as_int(x), CTRL, 0xF, 0xF, true);
    return x + __int_as_float(y);
}
__device__ inline float red16(float x) {
    x = dppadd<0x128>(x);  // row_ror:8
    x = dppadd<0x124>(x);  // row_ror:4
    x = dppadd<0x122>(x);  // row_ror:2
    x = dppadd<0x121>(x);  // row_ror:1
    return x;
}
__device__ inline float red64(float x) {
    x = red16(x);
    x += __shfl_xor(x, 16, 64);
    x += __shfl_xor(x, 32, 64);
    return x;
}

__device__ inline float dot8(const float4& q0, const float4& q1, const uint4& kk) {
    return q0.x * lo16(kk.x) + q0.y * hi16(kk.x)
         + q0.z * lo16(kk.y) + q0.w * hi16(kk.y)
         + q1.x * lo16(kk.z) + q1.y * hi16(kk.z)
         + q1.z * lo16(kk.w) + q1.w * hi16(kk.w);
}

// ---------------- CSR build ----------------
__global__ void k_init(int* cnt, int* fill, float* stats) {
    int i = blockIdx.x * blockDim.x + threadIdx.x;
    if (i < NN) { cnt[i] = 0; fill[i] = 0; }
    if (i < NLAYERS * NBUCK * 16) stats[i] = 0.f;
}

__global__ void k_count(const int* __restrict__ dst, int* __restrict__ cnt) {
    int e = blockIdx.x * blockDim.x + threadIdx.x;
    if (e < NE) atomicAdd(&cnt[dst[e]], 1);
}

__global__ __launch_bounds__(1024) void k_scan(const int* __restrict__ cnt, int* __restrict__ offs) {
    __shared__ int sh[1024];
    __shared__ int carry;
    if (threadIdx.x == 0) carry = 0;
    __syncthreads();
    for (int base = 0; base < NN; base += 1024) {
        int i = base + threadIdx.x;
        int v = (i < NN) ? cnt[i] : 0;
        sh[threadIdx.x] = v;
        __syncthreads();
        for (int off = 1; off < 1024; off <<= 1) {
            int t = (threadIdx.x >= off) ? sh[threadIdx.x - off] : 0;
            __syncthreads();
            sh[threadIdx.x] += t;
            __syncthreads();
        }
        int incl = sh[threadIdx.x];
        if (i < NN) offs[i] = carry + incl - v;
        __syncthreads();
        if (threadIdx.x == 1023) carry += sh[1023];
        __syncthreads();
    }
    if (threadIdx.x == 0) offs[NN] = carry;
}

__global__ void k_fill(const int* __restrict__ src, const int* __restrict__ dst,
                       const int* __restrict__ offs, int* __restrict__ fill,
                       int* __restrict__ col) {
    int e = blockIdx.x * blockDim.x + threadIdx.x;
    if (e < NE) {
        int d = dst[e];
        int p = offs[d] + atomicAdd(&fill[d], 1);
        col[p] = src[e];
    }
}

// ---------------- weight convert: fp32 -> bf16, [K][N] -> [N][K] ----------------
__global__ void k_wconv(const float* __restrict__ Wq, const float* __restrict__ Wk,
                        const float* __restrict__ Wv, const float* __restrict__ Ws,
                        const float* __restrict__ Wp,
                        unsigned short* __restrict__ wt_qkvs,   // [L][2048][128]
                        unsigned short* __restrict__ wpt) {     // [L][128][512]
    int id = blockIdx.x * blockDim.x + threadIdx.x;
    if (id < NLAYERS * 2048 * 128) {
        int l = id >> 18;
        int rem = id & 262143;
        int n = rem >> 7, k = rem & 127;
        int mat = n >> 9, wcol = n & 511;
        const float* W = (mat == 0) ? Wq : (mat == 1) ? Wk : (mat == 2) ? Wv : Ws;
        wt_qkvs[id] = f2bf(W[(size_t)l * 65536 + k * 512 + wcol]);
    } else if (id < NLAYERS * 2048 * 128 + NLAYERS * 128 * 512) {
        int id2 = id - NLAYERS * 2048 * 128;
        int l = id2 >> 16;
        int rem = id2 & 65535;
        int n = rem >> 9, k = rem & 511;
        wpt[(size_t)l * 65536 + n * 512 + k] = f2bf(Wp[(size_t)l * 65536 + k * 128 + n]);
    }
}

// ---------------- input projection ----------------
__global__ __launch_bounds__(128) void k_inproj(const float* __restrict__ x,
                                                const float* __restrict__ W,
                                                const float* __restrict__ b,
                                                float* __restrict__ h,
                                                unsigned short* __restrict__ h_bf) {
    int n = blockIdx.x;
    int j = threadIdx.x;
    float acc = b[j];
#pragma unroll
    for (int i = 0; i < 15; i++) acc += x[n * 15 + i] * W[i * 128 + j];
    h[n * 128 + j] = acc;
    h_bf[n * 128 + j] = f2bf(acc);
}

// ---------------- fused qkv+skip MFMA GEMM ----------------
// grid (79, 16): each block = 128 rows x 128 cols of the [N,2048] output.
// by>>2 selects the target matrix (q/k/v/skip) uniformly per block.
// Epilogue: pack bf16 tile in LDS (bank-swizzled), then coalesced uint4 stores.
__global__ __launch_bounds__(256) void k_qkvs_mfma(
    const unsigned short* __restrict__ h_bf,   // [NN][128]
    const unsigned short* __restrict__ Wt,     // [2048][128] layer slice
    const float* __restrict__ bq, const float* __restrict__ bk,
    const float* __restrict__ bv, const float* __restrict__ bs,
    unsigned short* __restrict__ qb16, unsigned short* __restrict__ kv16,
    unsigned short* __restrict__ sb16) {
    __shared__ unsigned short As[128 * 128];
    __shared__ unsigned short Bs[128 * 128];
    int row0 = blockIdx.x * 128;
    int n0 = blockIdx.y * 128;
    int t = threadIdx.x;
#pragma unroll
    for (int i = 0; i < 8; i++) {
        int c = t + i * 256;
        int r = c >> 4, cc = c & 15;
        int gr = row0 + r;
        uint4 v = make_uint4(0, 0, 0, 0);
        if (gr < NN) v = *(const uint4*)(h_bf + (size_t)gr * 128 + cc * 8);
        int sc = (r << 4) | (cc ^ (r & 7));
        *(uint4*)(As + sc * 8) = v;
    }
#pragma unroll
    for (int i = 0; i < 8; i++) {
        int c = t + i * 256;
        int r = c >> 4, cc = c & 15;
        uint4 v = *(const uint4*)(Wt + (size_t)(n0 + r) * 128 + cc * 8);
        int sc = (r << 4) | (cc ^ (r & 7));
        *(uint4*)(Bs + sc * 8) = v;
    }
    __syncthreads();
    int wave = t >> 6, lane = t & 63;
    int wr = (wave >> 1) * 64, wc = (wave & 1) * 64;
    int lr = lane & 15, lk = lane >> 4;
    f32x4 acc[4][4] = {};
#pragma unroll
    for (int ks = 0; ks < 4; ks++) {
        bf16x8 a[4], b[4];
#pragma unroll
        for (int mi = 0; mi < 4; mi++) {
            int r = wr + mi * 16 + lr;
            int cc = (ks * 4 + lk) ^ (r & 7);
            a[mi] = *(const bf16x8*)(As + (((r << 4) | cc) * 8));
        }
#pragma unroll
        for (int ni = 0; ni < 4; ni++) {
            int r = wc + ni * 16 + lr;
            int cc = (ks * 4 + lk) ^ (r & 7);
            b[ni] = *(const bf16x8*)(Bs + (((r << 4) | cc) * 8));
        }
#pragma unroll
        for (int mi = 0; mi < 4; mi++)
#pragma unroll
            for (int ni = 0; ni < 4; ni++)
                acc[mi][ni] = __builtin_amdgcn_mfma_f32_16x16x32_bf16(a[mi], b[ni], acc[mi][ni], 0, 0, 0);
    }
    // ---- epilogue: bias + bf16 pack into LDS (swizzled), coalesced stores ----
    int mat = blockIdx.y >> 2;           // uniform per block
    int wcol0 = n0 & 511;                // col base within the matrix
    const float* bias_p = (mat == 0) ? bq : (mat == 1) ? bk : (mat == 2) ? bv : bs;
    __syncthreads();                     // all MFMA LDS reads done, reuse As
#pragma unroll
    for (int ni = 0; ni < 4; ni++) {
        int colL = wc + ni * 16 + lr;    // local col 0..127
        float bias = bias_p[wcol0 + colL];
#pragma unroll
        for (int mi = 0; mi < 4; mi++) {
            int rowB = wr + mi * 16 + 4 * lk;
#pragma unroll
            for (int r = 0; r < 4; r++) {
                int row = rowB + r;
                unsigned int w = (unsigned int)(row * 64 + (colL >> 1));
                w ^= ((row >> 2) & 7) << 3;   // bank swizzle
                As[w * 2 + (colL & 1)] = f2bf(acc[mi][ni][r] + bias);
            }
        }
    }
    __syncthreads();
    unsigned short* outp = (mat == 0) ? qb16 : (mat == 3) ? sb16 : kv16;
    int rowStride = (mat == 1 || mat == 2) ? 1024 : 512;
    int cbase = wcol0 + ((mat == 2) ? 512 : 0);
#pragma unroll
    for (int i = 0; i < 8; i++) {
        int idx = t + i * 256;
        int row2 = idx >> 4;
        int c8 = (idx & 15) * 8;
        int gr = row0 + row2;
        if (gr < NN) {
            unsigned int wb = (unsigned int)(row2 * 64 + (idx & 15) * 4);
            wb ^= ((row2 >> 2) & 7) << 3;
            uint4 v = *(const uint4*)(As + wb * 2);
            *(uint4*)(outp + (size_t)gr * rowStride + cbase + c8) = v;
        }
    }
}

// ---------------- fused attention + beta gate + LN stats ----------------
// one block per node, one wave per head; 4 groups of 16 lanes, 2 ILP states
// per group (8 edges in flight/wave). q/skip/gated bf16. DPP reduces.
__global__ __launch_bounds__(256) void k_attn_beta(
    const unsigned short* __restrict__ qb16,
    const unsigned short* __restrict__ kv16,
    const unsigned short* __restrict__ sb16,
    const float* __restrict__ Wb,
    const int* __restrict__ offs, const int* __restrict__ col,
    unsigned short* __restrict__ gated16, float* __restrict__ stats) {
    int n = blockIdx.x;
    int head = threadIdx.x >> 6;
    int lane = threadIdx.x & 63;
    int g = lane >> 4;         // edge group 0..3
    int subl = lane & 15;      // 8 channels per lane
    const int hbase = head * CH;
    const int off = hbase + subl * 8;
    uint4 qq = *(const uint4*)(qb16 + (size_t)n * HCW + off);
    float4 q0 = {lo16(qq.x), hi16(qq.x), lo16(qq.y), hi16(qq.y)};
    float4 q1 = {lo16(qq.z), hi16(qq.z), lo16(qq.w), hi16(qq.w)};
    int beg = offs[n], end = offs[n + 1];
    const float scale = 0.08838834764831845f;  // 1/sqrt(128)

    float mA = -INFINITY, sA = 0.f, mB = -INFINITY, sB = 0.f;
    float4 a0A = {0.f, 0.f, 0.f, 0.f}, a1A = {0.f, 0.f, 0.f, 0.f};
    float4 a0B = {0.f, 0.f, 0.f, 0.f}, a1B = {0.f, 0.f, 0.f, 0.f};

    for (int p = beg + g; p < end; p += 8) {
        int pB = p + 4;
        bool hasB = (pB < end);
        int snA = col[p];
        int snB = hasB ? col[pB] : snA;
        const unsigned short* bA = kv16 + ((size_t)snA << 10) + off;
        const unsigned short* bB = kv16 + ((size_t)snB << 10) + off;
        uint4 kkA = *(const uint4*)bA;
        uint4 vvA = *(const uint4*)(bA + 512);
        uint4 kkB = *(const uint4*)bB;
        uint4 vvB = *(const uint4*)(bB + 512);
        float dA = dot8(q0, q1, kkA);
        float dB = dot8(q0, q1, kkB);
        dA = red16(dA);
        dB = red16(dB);
        float lA = dA * scale;
        float lB = dB * scale;
        if (lA <= mA + 8.f) {             // fast path: no rescale
            float w = __expf(lA - mA);
            sA += w;
            a0A.x += w * lo16(vvA.x); a0A.y += w * hi16(vvA.x);
            a0A.z += w * lo16(vvA.y); a0A.w += w * hi16(vvA.y);
            a1A.x += w * lo16(vvA.z); a1A.y += w * hi16(vvA.z);
            a1A.z += w * lo16(vvA.w); a1A.w += w * hi16(vvA.w);
        } else {                          // rescale (first edge & rare growth)
            float sc = __expf(mA - lA);   // mA=-inf -> 0
            sA = sA * sc + 1.f;
            a0A.x = a0A.x * sc + lo16(vvA.x); a0A.y = a0A.y * sc + hi16(vvA.x);
            a0A.z = a0A.z * sc + lo16(vvA.y); a0A.w = a0A.w * sc + hi16(vvA.y);
            a1A.x = a1A.x * sc + lo16(vvA.z); a1A.y = a1A.y * sc + hi16(vvA.z);
            a1A.z = a1A.z * sc + lo16(vvA.w); a1A.w = a1A.w * sc + hi16(vvA.w);
            mA = lA;
        }
        if (hasB) {
            if (lB <= mB + 8.f) {
                float w = __expf(lB - mB);
                sB += w;
                a0B.x += w * lo16(vvB.x); a0B.y += w * hi16(vvB.x);
                a0B.z += w * lo16(vvB.y); a0B.w += w * hi16(vvB.y);
                a1B.x += w * lo16(vvB.z); a1B.y += w * hi16(vvB.z);
                a1B.z += w * lo16(vvB.w); a1B.w += w * hi16(vvB.w);
            } else {
                float sc = __expf(mB - lB);
                sB = sB * sc + 1.f;
                a0B.x = a0B.x * sc + lo16(vvB.x); a0B.y = a0B.y * sc + hi16(vvB.x);
                a0B.z = a0B.z * sc + lo16(vvB.y); a0B.w = a0B.w * sc + hi16(vvB.y);
                a1B.x = a1B.x * sc + lo16(vvB.z); a1B.y = a1B.y * sc + hi16(vvB.z);
                a1B.z = a1B.z * sc + lo16(vvB.w); a1B.w = a1B.w * sc + hi16(vvB.w);
                mB = lB;
            }
        }
    }
    // merge B into A (per-lane)
    {
        float mn = fmaxf(mA, mB);
        float c1 = (sA > 0.f) ? __expf(mA - mn) : 0.f;
        float c2 = (sB > 0.f) ? __expf(mB - mn) : 0.f;
        sA = sA * c1 + sB * c2;
        a0A.x = a0A.x * c1 + a0B.x * c2; a0A.y = a0A.y * c1 + a0B.y * c2;
        a0A.z = a0A.z * c1 + a0B.z * c2; a0A.w = a0A.w * c1 + a0B.w * c2;
        a1A.x = a1A.x * c1 + a1B.x * c2; a1A.y = a1A.y * c1 + a1B.y * c2;
        a1A.z = a1A.z * c1 + a1B.z * c2; a1A.w = a1A.w * c1 + a1B.w * c2;
        mA = mn;
    }
    // merge the 4 group states (lane^16, lane^32 hold same channels)
#pragma unroll
    for (int off2 = 16; off2 <= 32; off2 <<= 1) {
        float m_o = __shfl_xor(mA, off2, 64);
        float s_o = __shfl_xor(sA, off2, 64);
        float4 b0, b1;
        b0.x = __shfl_xor(a0A.x, off2, 64); b0.y = __shfl_xor(a0A.y, off2, 64);
        b0.z = __shfl_xor(a0A.z, off2, 64); b0.w = __shfl_xor(a0A.w, off2, 64);
        b1.x = __shfl_xor(a1A.x, off2, 64); b1.y = __shfl_xor(a1A.y, off2, 64);
        b1.z = __shfl_xor(a1A.z, off2, 64); b1.w = __shfl_xor(a1A.w, off2, 64);
        float mn = fmaxf(mA, m_o);
        float c1 = (sA > 0.f) ? __expf(mA - mn) : 0.f;
        float c2 = (s_o > 0.f) ? __expf(m_o - mn) : 0.f;
        sA = sA * c1 + s_o * c2;
        a0A.x = a0A.x * c1 + b0.x * c2; a0A.y = a0A.y * c1 + b0.y * c2;
        a0A.z = a0A.z * c1 + b0.z * c2; a0A.w = a0A.w * c1 + b0.w * c2;
        a1A.x = a1A.x * c1 + b1.x * c2; a1A.y = a1A.y * c1 + b1.y * c2;
        a1A.z = a1A.z * c1 + b1.z * c2; a1A.w = a1A.w * c1 + b1.w * c2;
        mA = mn;
    }
    float inv = (sA > 0.f) ? 1.f / sA : 0.f;

    __shared__ float att_s[512];
    if (g == 0) {
        float4 o0 = {a0A.x * inv, a0A.y * inv, a0A.z * inv, a0A.w * inv};
        float4 o1 = {a1A.x * inv, a1A.y * inv, a1A.z * inv, a1A.w * inv};
        *(float4*)(att_s + off) = o0;
        *(float4*)(att_s + off + 4) = o1;
    }
    __syncthreads();

    // beta gate: channels c0 = head*128 + 2*lane, c1 = c0+1
    int c0 = hbase + lane * 2;
    float o0 = att_s[c0], o1 = att_s[c0 + 1];
    unsigned int sku = *(const unsigned int*)(sb16 + (size_t)n * HCW + c0);
    float skx = lo16(sku), sky = hi16(sku);
    float part = o0 * Wb[c0] + o1 * Wb[c0 + 1]
               + skx * Wb[512 + c0] + sky * Wb[512 + c0 + 1]
               + (o0 - skx) * Wb[1024 + c0] + (o1 - sky) * Wb[1024 + c0 + 1];
    part = red64(part);
    __shared__ float red[4];
    if (lane == 0) red[head] = part;
    __syncthreads();
    float tot = red[0] + red[1] + red[2] + red[3];
    float beta = 1.f / (1.f + __expf(-tot));
    float gx = beta * skx + (1.f - beta) * o0;
    float gy = beta * sky + (1.f - beta) * o1;
    unsigned int gu = (unsigned int)f2bf(gx) | ((unsigned int)f2bf(gy) << 16);
    *(unsigned int*)(gated16 + (size_t)n * HCW + c0) = gu;

    // LN partial sums on the rounded (stored) values -> bucketed atomics
    float gxr = lo16(gu), gyr = hi16(gu);
    float ls = red64(gxr + gyr);
    float lq = red64(gxr * gxr + gyr * gyr);
    __shared__ float r2[8];
    if (lane == 0) { r2[head] = ls; r2[4 + head] = lq; }
    __syncthreads();
    if (threadIdx.x == 0) {
        int b = n & (NBUCK - 1);
        atomicAdd(&stats[b * 16], r2[0] + r2[1] + r2[2] + r2[3]);
        atomicAdd(&stats[b * 16 + 1], r2[4] + r2[5] + r2[6] + r2[7]);
    }
}

// ---------------- LN + proj MFMA + residual + relu ----------------
// 64-row tiles, 8 waves (512 thr): wave w computes 16 rows x 64 cols.
__global__ __launch_bounds__(512) void k_proj_mfma(
    const unsigned short* __restrict__ gated16,   // [NN][512] bf16
    const unsigned short* __restrict__ Wpt,       // [128][512] layer slice
    const float* __restrict__ bp,
    const float* __restrict__ lw, const float* __restrict__ lb,
    const float* __restrict__ stats,
    float* __restrict__ h, unsigned short* __restrict__ h_bf) {
    __shared__ unsigned short As[64 * 128];    // 16KB
    __shared__ unsigned short Bs[128 * 128];   // 32KB
    int row0 = blockIdx.x * 64;
    int t = threadIdx.x;
    float ssum = 0.f, sq = 0.f;
#pragma unroll 16
    for (int i = 0; i < NBUCK; i++) { ssum += stats[i * 16]; sq += stats[i * 16 + 1]; }
    const float invM = 1.f / (NN * 512.f);
    float mean = ssum * invM;
    float ms = sq * invM - mean * mean;
    float rstd = 1.f / (sqrtf(fmaxf(ms, 0.f)) + LN_EPS);
    int wave = t >> 6, lane = t & 63;
    int wr = (wave >> 1) * 16, wc = (wave & 1) * 64;
    int lr = lane & 15, lk = lane >> 4;
    f32x4 acc[4] = {};
    for (int kc = 0; kc < 4; kc++) {
        __syncthreads();
#pragma unroll
        for (int i = 0; i < 2; i++) {
            int c = t + i * 512;
            int r = c >> 4, cc = c & 15;
            int gr = row0 + r;
            int gk = kc * 128 + cc * 8;
            unsigned short u[8];
            if (gr < NN) {
                uint4 gv = *(const uint4*)(gated16 + (size_t)gr * 512 + gk);
                float vals[8] = {lo16(gv.x), hi16(gv.x), lo16(gv.y), hi16(gv.y),
                                 lo16(gv.z), hi16(gv.z), lo16(gv.w), hi16(gv.w)};
#pragma unroll
                for (int j = 0; j < 8; j++)
                    u[j] = f2bf((vals[j] - mean) * rstd * lw[gk + j] + lb[gk + j]);
            } else {
#pragma unroll
                for (int j = 0; j < 8; j++) u[j] = 0;
            }
            int sc = (r << 4) | (cc ^ (r & 7));
            *(uint4*)(As + sc * 8) = *(uint4*)u;
        }
#pragma unroll
        for (int i = 0; i < 4; i++) {
            int c = t + i * 512;
            int r = c >> 4, cc = c & 15;
            uint4 v = *(const uint4*)(Wpt + (size_t)r * 512 + kc * 128 + cc * 8);
            int sc = (r << 4) | (cc ^ (r & 7));
            *(uint4*)(Bs + sc * 8) = v;
        }
        __syncthreads();
#pragma unroll
        for (int ks = 0; ks < 4; ks++) {
            bf16x8 a, b[4];
            {
                int r = wr + lr;
                int cc = (ks * 4 + lk) ^ (r & 7);
                a = *(const bf16x8*)(As + (((r << 4) | cc) * 8));
            }
#pragma unroll
            for (int ni = 0; ni < 4; ni++) {
                int r = wc + ni * 16 + lr;
                int cc = (ks * 4 + lk) ^ (r & 7);
                b[ni] = *(const bf16x8*)(Bs + (((r << 4) | cc) * 8));
            }
#pragma unroll
            for (int ni = 0; ni < 4; ni++)
                acc[ni] = __builtin_amdgcn_mfma_f32_16x16x32_bf16(a, b[ni], acc[ni], 0, 0, 0);
        }
    }
#pragma unroll
    for (int ni = 0; ni < 4; ni++) {
        int gc = wc + ni * 16 + lr;  // 0..127
        float bias = bp[gc];
        int gr0 = row0 + wr + 4 * lk;
#pragma unroll
        for (int r = 0; r < 4; r++) {
            int grr = gr0 + r;
            if (grr < NN) {
                float o = acc[ni][r] + bias + h[(size_t)grr * 128 + gc];
                o = fmaxf(o, 0.f);
                h[(size_t)grr * 128 + gc] = o;
                h_bf[(size_t)grr * 128 + gc] = f2bf(o);
            }
        }
    }
}

// ---------------- output projection ----------------
__global__ void k_out(const float* __restrict__ h, const float* __restrict__ W,
                      const float* __restrict__ b, float* __restrict__ out) {
    int i = blockIdx.x * blockDim.x + threadIdx.x;
    if (i >= NN * 5) return;
    int n = i / 5, j = i % 5;
    float acc = b[j];
    for (int k = 0; k < 128; k++) acc += h[(size_t)n * 128 + k] * W[k * 5 + j];
    out[i] = acc;
}

extern "C" void kernel_launch(void* const* d_in, const int* in_sizes, int n_in,
                              void* d_out, int out_size, void* d_ws, size_t ws_size,
                              hipStream_t stream) {
    const float* x     = (const float*)d_in[0];
    const int* ei      = (const int*)d_in[1];
    const float* W_in  = (const float*)d_in[2];
    const float* b_in  = (const float*)d_in[3];
    const float* W_out = (const float*)d_in[4];
    const float* b_out = (const float*)d_in[5];
    const float* Wq    = (const float*)d_in[6];
    const float* bq    = (const float*)d_in[7];
    const float* Wk    = (const float*)d_in[8];
    const float* bk    = (const float*)d_in[9];
    const float* Wv    = (const float*)d_in[10];
    const float* bv    = (const float*)d_in[11];
    const float* Wsk   = (const float*)d_in[12];
    const float* bsk   = (const float*)d_in[13];
    const float* Wbeta = (const float*)d_in[14];
    const float* ln_w  = (const float*)d_in[15];
    const float* ln_b  = (const float*)d_in[16];
    const float* Wproj = (const float*)d_in[17];
    const float* bproj = (const float*)d_in[18];
    float* out = (float*)d_out;

    // workspace layout
    float* h     = (float*)d_ws;                    // N*128 f32
    float* stats = h + (size_t)NN * 128;            // L*NBUCK*16
    int* offs = (int*)(stats + NLAYERS * NBUCK * 16);  // N+1
    int* cnt  = offs + (NN + 1);
    int* fill = cnt + NN;
    int* col  = fill + NN;                          // E
    unsigned short* h_bf = (unsigned short*)(((uintptr_t)(col + NE) + 15) & ~(uintptr_t)15);
    unsigned short* qb16 = h_bf + (size_t)NN * 128;                // N*512 (also gated)
    unsigned short* sb16 = qb16 + (size_t)NN * 512;                // N*512
    unsigned short* kv16 = sb16 + (size_t)NN * 512;                // N*1024 interleaved K|V
    unsigned short* wt_qkvs = kv16 + (size_t)NN * 1024;            // L*2048*128
    unsigned short* wpt = wt_qkvs + (size_t)NLAYERS * 2048 * 128;  // L*128*512
    unsigned short* gated16 = qb16;  // alias (block n reads q row n before writing)

    const int* src = ei;
    const int* dst = ei + NE;

    k_init<<<(NN + 255) / 256, 256, 0, stream>>>(cnt, fill, stats);
    k_count<<<(NE + 255) / 256, 256, 0, stream>>>(dst, cnt);
    k_scan<<<1, 1024, 0, stream>>>(cnt, offs);
    k_fill<<<(NE + 255) / 256, 256, 0, stream>>>(src, dst, offs, fill, col);
    {
        int tot = NLAYERS * 2048 * 128 + NLAYERS * 128 * 512;
        k_wconv<<<(tot + 255) / 256, 256, 0, stream>>>(Wq, Wk, Wv, Wsk, Wproj, wt_qkvs, wpt);
    }
    k_inproj<<<NN, 128, 0, stream>>>(x, W_in, b_in, h, h_bf);

    for (int l = 0; l < NLAYERS; ++l) {
        const unsigned short* Wt_ = wt_qkvs + (size_t)l * 2048 * 128;
        const unsigned short* Wp_ = wpt + (size_t)l * 128 * 512;
        const float* bq_ = bq + l * 512;
        const float* bk_ = bk + l * 512;
        const float* bv_ = bv + l * 512;
        const float* bs_ = bsk + l * 512;
        const float* Wb_ = Wbeta + (size_t)l * 1536;
        const float* lw_ = ln_w + l * 512;
        const float* lb_ = ln_b + l * 512;
        const float* bp_ = bproj + l * 128;
        float* st = stats + (size_t)l * NBUCK * 16;

        dim3 g1((NN + 127) / 128, 16);
        k_qkvs_mfma<<<g1, 256, 0, stream>>>(h_bf, Wt_, bq_, bk_, bv_, bs_,
                                            qb16, kv16, sb16);
        k_attn_beta<<<NN, 256, 0, stream>>>(qb16, kv16, sb16, Wb_, offs, col, gated16, st);
        k_proj_mfma<<<(NN + 63) / 64, 512, 0, stream>>>(gated16, Wp_, bp_, lw_, lb_, st, h, h_bf);
    }
    k_out<<<(NN * 5 + 255) / 256, 256, 0, stream>>>(h, W_out, b_out, out);
}

// Round 9
// 448.778 us; speedup vs baseline: 1.5123x; 1.0095x over previous
//
#include <hip/hip_runtime.h>
#include <math.h>

#define NN 10000
#define NE 160000
#define HCW 512
#define CH 128
#define NLAYERS 4
#define LN_EPS 1e-5f
#define NBUCK 128   // LN-stat atomic buckets, each on its own 64B line

typedef short bf16x8 __attribute__((ext_vector_type(8)));
typedef float f32x4 __attribute__((ext_vector_type(4)));

__device__ inline unsigned short f2bf(float f) {
    union { float f; unsigned int u; } x; x.f = f;
    unsigned int u = x.u;
    return (unsigned short)((u + 0x7FFFu + ((u >> 16) & 1u)) >> 16);
}
__device__ inline float bf2f(unsigned short s) {
    union { unsigned int u; float f; } x; x.u = ((unsigned int)s) << 16;
    return x.f;
}
__device__ inline float lo16(unsigned int u) {
    union { unsigned int x; float f; } v; v.x = u << 16; return v.f;
}
__device__ inline float hi16(unsigned int u) {
    union { unsigned int x; float f; } v; v.x = u & 0xffff0000u; return v.f;
}

// DPP row_ror add within 16-lane rows
template<int CTRL>
__device__ inline float dppadd(float x) {
    int y = __builtin_amdgcn_update_dpp(0, __float_as_int(x), CTRL, 0xF, 0xF, true);
    return x + __int_as_float(y);
}
__device__ inline float red16(float x) {
    x = dppadd<0x128>(x);  // row_ror:8
    x = dppadd<0x124>(x);  // row_ror:4
    x = dppadd<0x122>(x);  // row_ror:2
    x = dppadd<0x121>(x);  // row_ror:1
    return x;
}
__device__ inline float red64(float x) {
    x = red16(x);
    x += __shfl_xor(x, 16, 64);
    x += __shfl_xor(x, 32, 64);
    return x;
}

__device__ inline float dot8(const float4& q0, const float4& q1, const uint4& kk) {
    return q0.x * lo16(kk.x) + q0.y * hi16(kk.x)
         + q0.z * lo16(kk.y) + q0.w * hi16(kk.y)
         + q1.x * lo16(kk.z) + q1.y * hi16(kk.z)
         + q1.z * lo16(kk.w) + q1.w * hi16(kk.w);
}

// ---------------- CSR build ----------------
__global__ void k_init(int* cnt, int* fill, float* stats) {
    int i = blockIdx.x * blockDim.x + threadIdx.x;
    if (i < NN) { cnt[i] = 0; fill[i] = 0; }
    if (i < NLAYERS * NBUCK * 16) stats[i] = 0.f;
}

__global__ void k_count(const int* __restrict__ dst, int* __restrict__ cnt) {
    int e = blockIdx.x * blockDim.x + threadIdx.x;
    if (e < NE) atomicAdd(&cnt[dst[e]], 1);
}

__global__ __launch_bounds__(1024) void k_scan(const int* __restrict__ cnt, int* __restrict__ offs) {
    __shared__ int sh[1024];
    __shared__ int carry;
    if (threadIdx.x == 0) carry = 0;
    __syncthreads();
    for (int base = 0; base < NN; base += 1024) {
        int i = base + threadIdx.x;
        int v = (i < NN) ? cnt[i] : 0;
        sh[threadIdx.x] = v;
        __syncthreads();
        for (int off = 1; off < 1024; off <<= 1) {
            int t = (threadIdx.x >= off) ? sh[threadIdx.x - off] : 0;
            __syncthreads();
            sh[threadIdx.x] += t;
            __syncthreads();
        }
        int incl = sh[threadIdx.x];
        if (i < NN) offs[i] = carry + incl - v;
        __syncthreads();
        if (threadIdx.x == 1023) carry += sh[1023];
        __syncthreads();
    }
    if (threadIdx.x == 0) offs[NN] = carry;
}

__global__ void k_fill(const int* __restrict__ src, const int* __restrict__ dst,
                       const int* __restrict__ offs, int* __restrict__ fill,
                       int* __restrict__ col) {
    int e = blockIdx.x * blockDim.x + threadIdx.x;
    if (e < NE) {
        int d = dst[e];
        int p = offs[d] + atomicAdd(&fill[d], 1);
        col[p] = src[e];
    }
}

// ---------------- weight convert: fp32 -> bf16, [K][N] -> [N][K] ----------------
__global__ void k_wconv(const float* __restrict__ Wq, const float* __restrict__ Wk,
                        const float* __restrict__ Wv, const float* __restrict__ Ws,
                        const float* __restrict__ Wp,
                        unsigned short* __restrict__ wt_qkvs,   // [L][2048][128]
                        unsigned short* __restrict__ wpt) {     // [L][128][512]
    int id = blockIdx.x * blockDim.x + threadIdx.x;
    if (id < NLAYERS * 2048 * 128) {
        int l = id >> 18;
        int rem = id & 262143;
        int n = rem >> 7, k = rem & 127;
        int mat = n >> 9, wcol = n & 511;
        const float* W = (mat == 0) ? Wq : (mat == 1) ? Wk : (mat == 2) ? Wv : Ws;
        wt_qkvs[id] = f2bf(W[(size_t)l * 65536 + k * 512 + wcol]);
    } else if (id < NLAYERS * 2048 * 128 + NLAYERS * 128 * 512) {
        int id2 = id - NLAYERS * 2048 * 128;
        int l = id2 >> 16;
        int rem = id2 & 65535;
        int n = rem >> 9, k = rem & 511;
        wpt[(size_t)l * 65536 + n * 512 + k] = f2bf(Wp[(size_t)l * 65536 + k * 128 + n]);
    }
}

// ---------------- input projection ----------------
__global__ __launch_bounds__(128) void k_inproj(const float* __restrict__ x,
                                                const float* __restrict__ W,
                                                const float* __restrict__ b,
                                                float* __restrict__ h,
                                                unsigned short* __restrict__ h_bf) {
    int n = blockIdx.x;
    int j = threadIdx.x;
    float acc = b[j];
#pragma unroll
    for (int i = 0; i < 15; i++) acc += x[n * 15 + i] * W[i * 128 + j];
    h[n * 128 + j] = acc;
    h_bf[n * 128 + j] = f2bf(acc);
}

// ---------------- fused qkv+skip MFMA GEMM ----------------
// grid (79, 16): each block = 128 rows x 128 cols of the [N,2048] output.
// by>>2 selects the target matrix (q/k/v/skip) uniformly per block.
// Epilogue: pack bf16 tile in LDS (bank-swizzled), then coalesced uint4 stores.
__global__ __launch_bounds__(256) void k_qkvs_mfma(
    const unsigned short* __restrict__ h_bf,   // [NN][128]
    const unsigned short* __restrict__ Wt,     // [2048][128] layer slice
    const float* __restrict__ bq, const float* __restrict__ bk,
    const float* __restrict__ bv, const float* __restrict__ bs,
    unsigned short* __restrict__ qb16, unsigned short* __restrict__ kv16,
    unsigned short* __restrict__ sb16) {
    __shared__ unsigned short As[128 * 128];
    __shared__ unsigned short Bs[128 * 128];
    int row0 = blockIdx.x * 128;
    int n0 = blockIdx.y * 128;
    int t = threadIdx.x;
#pragma unroll
    for (int i = 0; i < 8; i++) {
        int c = t + i * 256;
        int r = c >> 4, cc = c & 15;
        int gr = row0 + r;
        uint4 v = make_uint4(0, 0, 0, 0);
        if (gr < NN) v = *(const uint4*)(h_bf + (size_t)gr * 128 + cc * 8);
        int sc = (r << 4) | (cc ^ (r & 7));
        *(uint4*)(As + sc * 8) = v;
    }
#pragma unroll
    for (int i = 0; i < 8; i++) {
        int c = t + i * 256;
        int r = c >> 4, cc = c & 15;
        uint4 v = *(const uint4*)(Wt + (size_t)(n0 + r) * 128 + cc * 8);
        int sc = (r << 4) | (cc ^ (r & 7));
        *(uint4*)(Bs + sc * 8) = v;
    }
    __syncthreads();
    int wave = t >> 6, lane = t & 63;
    int wr = (wave >> 1) * 64, wc = (wave & 1) * 64;
    int lr = lane & 15, lk = lane >> 4;
    f32x4 acc[4][4] = {};
#pragma unroll
    for (int ks = 0; ks < 4; ks++) {
        bf16x8 a[4], b[4];
#pragma unroll
        for (int mi = 0; mi < 4; mi++) {
            int r = wr + mi * 16 + lr;
            int cc = (ks * 4 + lk) ^ (r & 7);
            a[mi] = *(const bf16x8*)(As + (((r << 4) | cc) * 8));
        }
#pragma unroll
        for (int ni = 0; ni < 4; ni++) {
            int r = wc + ni * 16 + lr;
            int cc = (ks * 4 + lk) ^ (r & 7);
            b[ni] = *(const bf16x8*)(Bs + (((r << 4) | cc) * 8));
        }
#pragma unroll
        for (int mi = 0; mi < 4; mi++)
#pragma unroll
            for (int ni = 0; ni < 4; ni++)
                acc[mi][ni] = __builtin_amdgcn_mfma_f32_16x16x32_bf16(a[mi], b[ni], acc[mi][ni], 0, 0, 0);
    }
    // ---- epilogue: bias + bf16 pack into LDS (swizzled), coalesced stores ----
    int mat = blockIdx.y >> 2;           // uniform per block
    int wcol0 = n0 & 511;                // col base within the matrix
    const float* bias_p = (mat == 0) ? bq : (mat == 1) ? bk : (mat == 2) ? bv : bs;
    __syncthreads();                     // all MFMA LDS reads done, reuse As
#pragma unroll
    for (int ni = 0; ni < 4; ni++) {
        int colL = wc + ni * 16 + lr;    // local col 0..127
        float bias = bias_p[wcol0 + colL];
#pragma unroll
        for (int mi = 0; mi < 4; mi++) {
            int rowB = wr + mi * 16 + 4 * lk;
#pragma unroll
            for (int r = 0; r < 4; r++) {
                int row = rowB + r;
                unsigned int w = (unsigned int)(row * 64 + (colL >> 1));
                w ^= ((row >> 2) & 7) << 3;   // bank swizzle
                As[w * 2 + (colL & 1)] = f2bf(acc[mi][ni][r] + bias);
            }
        }
    }
    __syncthreads();
    unsigned short* outp = (mat == 0) ? qb16 : (mat == 3) ? sb16 : kv16;
    int rowStride = (mat == 1 || mat == 2) ? 1024 : 512;
    int cbase = wcol0 + ((mat == 2) ? 512 : 0);
#pragma unroll
    for (int i = 0; i < 8; i++) {
        int idx = t + i * 256;
        int row2 = idx >> 4;
        int c8 = (idx & 15) * 8;
        int gr = row0 + row2;
        if (gr < NN) {
            unsigned int wb = (unsigned int)(row2 * 64 + (idx & 15) * 4);
            wb ^= ((row2 >> 2) & 7) << 3;
            uint4 v = *(const uint4*)(As + wb * 2);
            *(uint4*)(outp + (size_t)gr * rowStride + cbase + c8) = v;
        }
    }
}

// ---------------- fused attention + beta gate + LN stats ----------------
// ONE WAVE PER NODE (4 nodes/block). Lane covers channels
// (lane>>4)*128 + (lane&15)*8 .. +7 -> the 64 lanes span all 512 channels,
// all 4 heads served by one pass over the edge list. ILP-4 edge states.
// Per-head logits live in 16-lane groups via red16; no cross-head merges.
__global__ __launch_bounds__(256) void k_attn_beta(
    const unsigned short* __restrict__ qb16,
    const unsigned short* __restrict__ kv16,
    const unsigned short* __restrict__ sb16,
    const float* __restrict__ Wb,
    const int* __restrict__ offs, const int* __restrict__ col,
    unsigned short* __restrict__ gated16, float* __restrict__ stats) {
    int wave = threadIdx.x >> 6;
    int lane = threadIdx.x & 63;
    int n = blockIdx.x * 4 + wave;          // NN % 4 == 0
    const int off = ((lane >> 4) << 7) + ((lane & 15) << 3);
    uint4 qq = *(const uint4*)(qb16 + (size_t)n * HCW + off);
    float4 q0 = {lo16(qq.x), hi16(qq.x), lo16(qq.y), hi16(qq.y)};
    float4 q1 = {lo16(qq.z), hi16(qq.z), lo16(qq.w), hi16(qq.w)};
    int beg = offs[n], end = offs[n + 1];
    const float scale = 0.08838834764831845f;  // 1/sqrt(128)

    float m[4], s[4];
    float4 a0[4], a1[4];
#pragma unroll
    for (int i = 0; i < 4; i++) {
        m[i] = -INFINITY; s[i] = 0.f;
        a0[i] = make_float4(0.f, 0.f, 0.f, 0.f);
        a1[i] = make_float4(0.f, 0.f, 0.f, 0.f);
    }

    for (int p = beg; p < end; p += 4) {
        uint4 kk[4], vv[4];
        bool has[4];
#pragma unroll
        for (int i = 0; i < 4; i++) {
            int pi = p + i;
            has[i] = (pi < end);
            int sn = col[has[i] ? pi : p];
            const unsigned short* bp_ = kv16 + ((size_t)sn << 10) + off;
            kk[i] = *(const uint4*)bp_;
            vv[i] = *(const uint4*)(bp_ + 512);
        }
#pragma unroll
        for (int i = 0; i < 4; i++) {
            if (!has[i]) continue;
            float l = red16(dot8(q0, q1, kk[i])) * scale;
            if (l <= m[i] + 8.f) {            // fast path: no rescale
                float w = __expf(l - m[i]);
                s[i] += w;
                a0[i].x += w * lo16(vv[i].x); a0[i].y += w * hi16(vv[i].x);
                a0[i].z += w * lo16(vv[i].y); a0[i].w += w * hi16(vv[i].y);
                a1[i].x += w * lo16(vv[i].z); a1[i].y += w * hi16(vv[i].z);
                a1[i].z += w * lo16(vv[i].w); a1[i].w += w * hi16(vv[i].w);
            } else {                          // rescale (first edge & rare growth)
                float sc = __expf(m[i] - l);  // m=-inf -> 0
                s[i] = s[i] * sc + 1.f;
                a0[i].x = a0[i].x * sc + lo16(vv[i].x); a0[i].y = a0[i].y * sc + hi16(vv[i].x);
                a0[i].z = a0[i].z * sc + lo16(vv[i].y); a0[i].w = a0[i].w * sc + hi16(vv[i].y);
                a1[i].x = a1[i].x * sc + lo16(vv[i].z); a1[i].y = a1[i].y * sc + hi16(vv[i].z);
                a1[i].z = a1[i].z * sc + lo16(vv[i].w); a1[i].w = a1[i].w * sc + hi16(vv[i].w);
                m[i] = l;
            }
        }
    }
    // merge states 1..3 into state 0 (per-lane; same channels)
#pragma unroll
    for (int i = 1; i < 4; i++) {
        float mn = fmaxf(m[0], m[i]);
        float c1 = (s[0] > 0.f) ? __expf(m[0] - mn) : 0.f;
        float c2 = (s[i] > 0.f) ? __expf(m[i] - mn) : 0.f;
        s[0] = s[0] * c1 + s[i] * c2;
        a0[0].x = a0[0].x * c1 + a0[i].x * c2; a0[0].y = a0[0].y * c1 + a0[i].y * c2;
        a0[0].z = a0[0].z * c1 + a0[i].z * c2; a0[0].w = a0[0].w * c1 + a0[i].w * c2;
        a1[0].x = a1[0].x * c1 + a1[i].x * c2; a1[0].y = a1[0].y * c1 + a1[i].y * c2;
        a1[0].z = a1[0].z * c1 + a1[i].z * c2; a1[0].w = a1[0].w * c1 + a1[i].w * c2;
        m[0] = mn;
    }
    float inv = (s[0] > 0.f) ? 1.f / s[0] : 0.f;
    float o[8] = {a0[0].x * inv, a0[0].y * inv, a0[0].z * inv, a0[0].w * inv,
                  a1[0].x * inv, a1[0].y * inv, a1[0].z * inv, a1[0].w * inv};

    // skip row (8 channels per lane)
    uint4 sku = *(const uint4*)(sb16 + (size_t)n * HCW + off);
    float sk[8] = {lo16(sku.x), hi16(sku.x), lo16(sku.y), hi16(sku.y),
                   lo16(sku.z), hi16(sku.z), lo16(sku.w), hi16(sku.w)};

    // beta gate: partial over this lane's 8 channels, then wave reduce
    float part = 0.f;
#pragma unroll
    for (int j = 0; j < 8; j++) {
        int c = off + j;
        part += o[j] * Wb[c] + sk[j] * Wb[512 + c] + (o[j] - sk[j]) * Wb[1024 + c];
    }
    part = red64(part);
    float beta = 1.f / (1.f + __expf(-part));

    unsigned int gu[4];
    float ls = 0.f, lq = 0.f;
#pragma unroll
    for (int j = 0; j < 4; j++) {
        float gx = beta * sk[2 * j] + (1.f - beta) * o[2 * j];
        float gy = beta * sk[2 * j + 1] + (1.f - beta) * o[2 * j + 1];
        gu[j] = (unsigned int)f2bf(gx) | ((unsigned int)f2bf(gy) << 16);
        float gxr = lo16(gu[j]), gyr = hi16(gu[j]);
        ls += gxr + gyr;
        lq += gxr * gxr + gyr * gyr;
    }
    *(uint4*)(gated16 + (size_t)n * HCW + off) = *(uint4*)gu;

    // LN partial sums -> bucketed atomics (one 64B line per bucket)
    ls = red64(ls);
    lq = red64(lq);
    __shared__ float r2[8];
    if (lane == 0) { r2[wave] = ls; r2[4 + wave] = lq; }
    __syncthreads();
    if (threadIdx.x == 0) {
        int b = blockIdx.x & (NBUCK - 1);
        atomicAdd(&stats[b * 16], r2[0] + r2[1] + r2[2] + r2[3]);
        atomicAdd(&stats[b * 16 + 1], r2[4] + r2[5] + r2[6] + r2[7]);
    }
}

// ---------------- LN + proj MFMA + residual + relu ----------------
// 64-row tiles, 8 waves (512 thr): wave w computes 16 rows x 64 cols.
__global__ __launch_bounds__(512) void k_proj_mfma(
    const unsigned short* __restrict__ gated16,   // [NN][512] bf16
    const unsigned short* __restrict__ Wpt,       // [128][512] layer slice
    const float* __restrict__ bp,
    const float* __restrict__ lw, const float* __restrict__ lb,
    const float* __restrict__ stats,
    float* __restrict__ h, unsigned short* __restrict__ h_bf) {
    __shared__ unsigned short As[64 * 128];    // 16KB
    __shared__ unsigned short Bs[128 * 128];   // 32KB
    int row0 = blockIdx.x * 64;
    int t = threadIdx.x;
    float ssum = 0.f, sq = 0.f;
#pragma unroll 16
    for (int i = 0; i < NBUCK; i++) { ssum += stats[i * 16]; sq += stats[i * 16 + 1]; }
    const float invM = 1.f / (NN * 512.f);
    float mean = ssum * invM;
    float ms = sq * invM - mean * mean;
    float rstd = 1.f / (sqrtf(fmaxf(ms, 0.f)) + LN_EPS);
    int wave = t >> 6, lane = t & 63;
    int wr = (wave >> 1) * 16, wc = (wave & 1) * 64;
    int lr = lane & 15, lk = lane >> 4;
    f32x4 acc[4] = {};
    for (int kc = 0; kc < 4; kc++) {
        __syncthreads();
#pragma unroll
        for (int i = 0; i < 2; i++) {
            int c = t + i * 512;
            int r = c >> 4, cc = c & 15;
            int gr = row0 + r;
            int gk = kc * 128 + cc * 8;
            unsigned short u[8];
            if (gr < NN) {
                uint4 gv = *(const uint4*)(gated16 + (size_t)gr * 512 + gk);
                float vals[8] = {lo16(gv.x), hi16(gv.x), lo16(gv.y), hi16(gv.y),
                                 lo16(gv.z), hi16(gv.z), lo16(gv.w), hi16(gv.w)};
#pragma unroll
                for (int j = 0; j < 8; j++)
                    u[j] = f2bf((vals[j] - mean) * rstd * lw[gk + j] + lb[gk + j]);
            } else {
#pragma unroll
                for (int j = 0; j < 8; j++) u[j] = 0;
            }
            int sc = (r << 4) | (cc ^ (r & 7));
            *(uint4*)(As + sc * 8) = *(uint4*)u;
        }
#pragma unroll
        for (int i = 0; i < 4; i++) {
            int c = t + i * 512;
            int r = c >> 4, cc = c & 15;
            uint4 v = *(const uint4*)(Wpt + (size_t)r * 512 + kc * 128 + cc * 8);
            int sc = (r << 4) | (cc ^ (r & 7));
            *(uint4*)(Bs + sc * 8) = v;
        }
        __syncthreads();
#pragma unroll
        for (int ks = 0; ks < 4; ks++) {
            bf16x8 a, b[4];
            {
                int r = wr + lr;
                int cc = (ks * 4 + lk) ^ (r & 7);
                a = *(const bf16x8*)(As + (((r << 4) | cc) * 8));
            }
#pragma unroll
            for (int ni = 0; ni < 4; ni++) {
                int r = wc + ni * 16 + lr;
                int cc = (ks * 4 + lk) ^ (r & 7);
                b[ni] = *(const bf16x8*)(Bs + (((r << 4) | cc) * 8));
            }
#pragma unroll
            for (int ni = 0; ni < 4; ni++)
                acc[ni] = __builtin_amdgcn_mfma_f32_16x16x32_bf16(a, b[ni], acc[ni], 0, 0, 0);
        }
    }
#pragma unroll
    for (int ni = 0; ni < 4; ni++) {
        int gc = wc + ni * 16 + lr;  // 0..127
        float bias = bp[gc];
        int gr0 = row0 + wr + 4 * lk;
#pragma unroll
        for (int r = 0; r < 4; r++) {
            int grr = gr0 + r;
            if (grr < NN) {
                float o = acc[ni][r] + bias + h[(size_t)grr * 128 + gc];
                o = fmaxf(o, 0.f);
                h[(size_t)grr * 128 + gc] = o;
                h_bf[(size_t)grr * 128 + gc] = f2bf(o);
            }
        }
    }
}

// ---------------- output projection ----------------
__global__ void k_out(const float* __restrict__ h, const float* __restrict__ W,
                      const float* __restrict__ b, float* __restrict__ out) {
    int i = blockIdx.x * blockDim.x + threadIdx.x;
    if (i >= NN * 5) return;
    int n = i / 5, j = i % 5;
    float acc = b[j];
    for (int k = 0; k < 128; k++) acc += h[(size_t)n * 128 + k] * W[k * 5 + j];
    out[i] = acc;
}

extern "C" void kernel_launch(void* const* d_in, const int* in_sizes, int n_in,
                              void* d_out, int out_size, void* d_ws, size_t ws_size,
                              hipStream_t stream) {
    const float* x     = (const float*)d_in[0];
    const int* ei      = (const int*)d_in[1];
    const float* W_in  = (const float*)d_in[2];
    const float* b_in  = (const float*)d_in[3];
    const float* W_out = (const float*)d_in[4];
    const float* b_out = (const float*)d_in[5];
    const float* Wq    = (const float*)d_in[6];
    const float* bq    = (const float*)d_in[7];
    const float* Wk    = (const float*)d_in[8];
    const float* bk    = (const float*)d_in[9];
    const float* Wv    = (const float*)d_in[10];
    const float* bv    = (const float*)d_in[11];
    const float* Wsk   = (const float*)d_in[12];
    const float* bsk   = (const float*)d_in[13];
    const float* Wbeta = (const float*)d_in[14];
    const float* ln_w  = (const float*)d_in[15];
    const float* ln_b  = (const float*)d_in[16];
    const float* Wproj = (const float*)d_in[17];
    const float* bproj = (const float*)d_in[18];
    float* out = (float*)d_out;

    // workspace layout
    float* h     = (float*)d_ws;                    // N*128 f32
    float* stats = h + (size_t)NN * 128;            // L*NBUCK*16
    int* offs = (int*)(stats + NLAYERS * NBUCK * 16);  // N+1
    int* cnt  = offs + (NN + 1);
    int* fill = cnt + NN;
    int* col  = fill + NN;                          // E
    unsigned short* h_bf = (unsigned short*)(((uintptr_t)(col + NE) + 15) & ~(uintptr_t)15);
    unsigned short* qb16 = h_bf + (size_t)NN * 128;                // N*512 (also gated)
    unsigned short* sb16 = qb16 + (size_t)NN * 512;                // N*512
    unsigned short* kv16 = sb16 + (size_t)NN * 512;                // N*1024 interleaved K|V
    unsigned short* wt_qkvs = kv16 + (size_t)NN * 1024;            // L*2048*128
    unsigned short* wpt = wt_qkvs + (size_t)NLAYERS * 2048 * 128;  // L*128*512
    unsigned short* gated16 = qb16;  // alias (wave n reads q row n before writing)

    const int* src = ei;
    const int* dst = ei + NE;

    k_init<<<(NN + 255) / 256, 256, 0, stream>>>(cnt, fill, stats);
    k_count<<<(NE + 255) / 256, 256, 0, stream>>>(dst, cnt);
    k_scan<<<1, 1024, 0, stream>>>(cnt, offs);
    k_fill<<<(NE + 255) / 256, 256, 0, stream>>>(src, dst, offs, fill, col);
    {
        int tot = NLAYERS * 2048 * 128 + NLAYERS * 128 * 512;
        k_wconv<<<(tot + 255) / 256, 256, 0, stream>>>(Wq, Wk, Wv, Wsk, Wproj, wt_qkvs, wpt);
    }
    k_inproj<<<NN, 128, 0, stream>>>(x, W_in, b_in, h, h_bf);

    for (int l = 0; l < NLAYERS; ++l) {
        const unsigned short* Wt_ = wt_qkvs + (size_t)l * 2048 * 128;
        const unsigned short* Wp_ = wpt + (size_t)l * 128 * 512;
        const float* bq_ = bq + l * 512;
        const float* bk_ = bk + l * 512;
        const float* bv_ = bv + l * 512;
        const float* bs_ = bsk + l * 512;
        const float* Wb_ = Wbeta + (size_t)l * 1536;
        const float* lw_ = ln_w + l * 512;
        const float* lb_ = ln_b + l * 512;
        const float* bp_ = bproj + l * 128;
        float* st = stats + (size_t)l * NBUCK * 16;

        dim3 g1((NN + 127) / 128, 16);
        k_qkvs_mfma<<<g1, 256, 0, stream>>>(h_bf, Wt_, bq_, bk_, bv_, bs_,
                                            qb16, kv16, sb16);
        k_attn_beta<<<NN / 4, 256, 0, stream>>>(qb16, kv16, sb16, Wb_, offs, col, gated16, st);
        k_proj_mfma<<<(NN + 63) / 64, 512, 0, stream>>>(gated16, Wp_, bp_, lw_, lb_, st, h, h_bf);
    }
    k_out<<<(NN * 5 + 255) / 256, 256, 0, stream>>>(h, W_out, b_out, out);
}

// Round 10
// 446.358 us; speedup vs baseline: 1.5205x; 1.0054x over previous
//
#include <hip/hip_runtime.h>
#include <math.h>

#define NN 10000
#define NE 160000
#define HCW 512
#define CH 128
#define NLAYERS 4
#define LN_EPS 1e-5f
#define NBUCK 128   // LN-stat atomic buckets, each on its own 64B line

typedef short bf16x8 __attribute__((ext_vector_type(8)));
typedef float f32x4 __attribute__((ext_vector_type(4)));

__device__ inline unsigned short f2bf(float f) {
    union { float f; unsigned int u; } x; x.f = f;
    unsigned int u = x.u;
    return (unsigned short)((u + 0x7FFFu + ((u >> 16) & 1u)) >> 16);
}
__device__ inline float bf2f(unsigned short s) {
    union { unsigned int u; float f; } x; x.u = ((unsigned int)s) << 16;
    return x.f;
}
__device__ inline float lo16(unsigned int u) {
    union { unsigned int x; float f; } v; v.x = u << 16; return v.f;
}
__device__ inline float hi16(unsigned int u) {
    union { unsigned int x; float f; } v; v.x = u & 0xffff0000u; return v.f;
}

// DPP row_ror add within 16-lane rows
template<int CTRL>
__device__ inline float dppadd(float x) {
    int y = __builtin_amdgcn_update_dpp(0, __float_as_int(x), CTRL, 0xF, 0xF, true);
    return x + __int_as_float(y);
}
__device__ inline float red16(float x) {
    x = dppadd<0x128>(x);  // row_ror:8
    x = dppadd<0x124>(x);  // row_ror:4
    x = dppadd<0x122>(x);  // row_ror:2
    x = dppadd<0x121>(x);  // row_ror:1
    return x;
}
__device__ inline float red64(float x) {
    x = red16(x);
    x += __shfl_xor(x, 16, 64);
    x += __shfl_xor(x, 32, 64);
    return x;
}

__device__ inline float dot8(const float4& q0, const float4& q1, const uint4& kk) {
    return q0.x * lo16(kk.x) + q0.y * hi16(kk.x)
         + q0.z * lo16(kk.y) + q0.w * hi16(kk.y)
         + q1.x * lo16(kk.z) + q1.y * hi16(kk.z)
         + q1.z * lo16(kk.w) + q1.w * hi16(kk.w);
}

// ---------------- CSR build ----------------
__global__ void k_init(int* cnt, int* fill, float* stats) {
    int i = blockIdx.x * blockDim.x + threadIdx.x;
    if (i < NN) { cnt[i] = 0; fill[i] = 0; }
    if (i < NLAYERS * NBUCK * 16) stats[i] = 0.f;
}

__global__ void k_count(const int* __restrict__ dst, int* __restrict__ cnt) {
    int e = blockIdx.x * blockDim.x + threadIdx.x;
    if (e < NE) atomicAdd(&cnt[dst[e]], 1);
}

__global__ __launch_bounds__(1024) void k_scan(const int* __restrict__ cnt, int* __restrict__ offs) {
    __shared__ int sh[1024];
    __shared__ int carry;
    if (threadIdx.x == 0) carry = 0;
    __syncthreads();
    for (int base = 0; base < NN; base += 1024) {
        int i = base + threadIdx.x;
        int v = (i < NN) ? cnt[i] : 0;
        sh[threadIdx.x] = v;
        __syncthreads();
        for (int off = 1; off < 1024; off <<= 1) {
            int t = (threadIdx.x >= off) ? sh[threadIdx.x - off] : 0;
            __syncthreads();
            sh[threadIdx.x] += t;
            __syncthreads();
        }
        int incl = sh[threadIdx.x];
        if (i < NN) offs[i] = carry + incl - v;
        __syncthreads();
        if (threadIdx.x == 1023) carry += sh[1023];
        __syncthreads();
    }
    if (threadIdx.x == 0) offs[NN] = carry;
}

__global__ void k_fill(const int* __restrict__ src, const int* __restrict__ dst,
                       const int* __restrict__ offs, int* __restrict__ fill,
                       int* __restrict__ col) {
    int e = blockIdx.x * blockDim.x + threadIdx.x;
    if (e < NE) {
        int d = dst[e];
        int p = offs[d] + atomicAdd(&fill[d], 1);
        col[p] = src[e];
    }
}

// ---------------- weight convert: fp32 -> bf16, [K][N] -> [N][K] ----------------
__global__ void k_wconv(const float* __restrict__ Wq, const float* __restrict__ Wk,
                        const float* __restrict__ Wv, const float* __restrict__ Ws,
                        const float* __restrict__ Wp,
                        unsigned short* __restrict__ wt_qkvs,   // [L][2048][128]
                        unsigned short* __restrict__ wpt) {     // [L][128][512]
    int id = blockIdx.x * blockDim.x + threadIdx.x;
    if (id < NLAYERS * 2048 * 128) {
        int l = id >> 18;
        int rem = id & 262143;
        int n = rem >> 7, k = rem & 127;
        int mat = n >> 9, wcol = n & 511;
        const float* W = (mat == 0) ? Wq : (mat == 1) ? Wk : (mat == 2) ? Wv : Ws;
        wt_qkvs[id] = f2bf(W[(size_t)l * 65536 + k * 512 + wcol]);
    } else if (id < NLAYERS * 2048 * 128 + NLAYERS * 128 * 512) {
        int id2 = id - NLAYERS * 2048 * 128;
        int l = id2 >> 16;
        int rem = id2 & 65535;
        int n = rem >> 9, k = rem & 511;
        wpt[(size_t)l * 65536 + n * 512 + k] = f2bf(Wp[(size_t)l * 65536 + k * 128 + n]);
    }
}

// ---------------- input projection ----------------
__global__ __launch_bounds__(128) void k_inproj(const float* __restrict__ x,
                                                const float* __restrict__ W,
                                                const float* __restrict__ b,
                                                float* __restrict__ h,
                                                unsigned short* __restrict__ h_bf) {
    int n = blockIdx.x;
    int j = threadIdx.x;
    float acc = b[j];
#pragma unroll
    for (int i = 0; i < 15; i++) acc += x[n * 15 + i] * W[i * 128 + j];
    h[n * 128 + j] = acc;
    h_bf[n * 128 + j] = f2bf(acc);
}

// ---------------- fused qkv+skip MFMA GEMM ----------------
// grid (79, 16): each block = 128 rows x 128 cols of the [N,2048] output.
// by>>2 selects the target matrix (q/k/v/skip) uniformly per block.
// Epilogue: pack bf16 tile in LDS (bank-swizzled), then coalesced uint4 stores.
__global__ __launch_bounds__(256) void k_qkvs_mfma(
    const unsigned short* __restrict__ h_bf,   // [NN][128]
    const unsigned short* __restrict__ Wt,     // [2048][128] layer slice
    const float* __restrict__ bq, const float* __restrict__ bk,
    const float* __restrict__ bv, const float* __restrict__ bs,
    unsigned short* __restrict__ qb16, unsigned short* __restrict__ kv16,
    unsigned short* __restrict__ sb16) {
    __shared__ unsigned short As[128 * 128];
    __shared__ unsigned short Bs[128 * 128];
    int row0 = blockIdx.x * 128;
    int n0 = blockIdx.y * 128;
    int t = threadIdx.x;
#pragma unroll
    for (int i = 0; i < 8; i++) {
        int c = t + i * 256;
        int r = c >> 4, cc = c & 15;
        int gr = row0 + r;
        uint4 v = make_uint4(0, 0, 0, 0);
        if (gr < NN) v = *(const uint4*)(h_bf + (size_t)gr * 128 + cc * 8);
        int sc = (r << 4) | (cc ^ (r & 7));
        *(uint4*)(As + sc * 8) = v;
    }
#pragma unroll
    for (int i = 0; i < 8; i++) {
        int c = t + i * 256;
        int r = c >> 4, cc = c & 15;
        uint4 v = *(const uint4*)(Wt + (size_t)(n0 + r) * 128 + cc * 8);
        int sc = (r << 4) | (cc ^ (r & 7));
        *(uint4*)(Bs + sc * 8) = v;
    }
    __syncthreads();
    int wave = t >> 6, lane = t & 63;
    int wr = (wave >> 1) * 64, wc = (wave & 1) * 64;
    int lr = lane & 15, lk = lane >> 4;
    f32x4 acc[4][4] = {};
#pragma unroll
    for (int ks = 0; ks < 4; ks++) {
        bf16x8 a[4], b[4];
#pragma unroll
        for (int mi = 0; mi < 4; mi++) {
            int r = wr + mi * 16 + lr;
            int cc = (ks * 4 + lk) ^ (r & 7);
            a[mi] = *(const bf16x8*)(As + (((r << 4) | cc) * 8));
        }
#pragma unroll
        for (int ni = 0; ni < 4; ni++) {
            int r = wc + ni * 16 + lr;
            int cc = (ks * 4 + lk) ^ (r & 7);
            b[ni] = *(const bf16x8*)(Bs + (((r << 4) | cc) * 8));
        }
#pragma unroll
        for (int mi = 0; mi < 4; mi++)
#pragma unroll
            for (int ni = 0; ni < 4; ni++)
                acc[mi][ni] = __builtin_amdgcn_mfma_f32_16x16x32_bf16(a[mi], b[ni], acc[mi][ni], 0, 0, 0);
    }
    // ---- epilogue: bias + bf16 pack into LDS (swizzled), coalesced stores ----
    int mat = blockIdx.y >> 2;           // uniform per block
    int wcol0 = n0 & 511;                // col base within the matrix
    const float* bias_p = (mat == 0) ? bq : (mat == 1) ? bk : (mat == 2) ? bv : bs;
    __syncthreads();                     // all MFMA LDS reads done, reuse As
#pragma unroll
    for (int ni = 0; ni < 4; ni++) {
        int colL = wc + ni * 16 + lr;    // local col 0..127
        float bias = bias_p[wcol0 + colL];
#pragma unroll
        for (int mi = 0; mi < 4; mi++) {
            int rowB = wr + mi * 16 + 4 * lk;
#pragma unroll
            for (int r = 0; r < 4; r++) {
                int row = rowB + r;
                unsigned int w = (unsigned int)(row * 64 + (colL >> 1));
                w ^= ((row >> 2) & 7) << 3;   // bank swizzle
                As[w * 2 + (colL & 1)] = f2bf(acc[mi][ni][r] + bias);
            }
        }
    }
    __syncthreads();
    unsigned short* outp = (mat == 0) ? qb16 : (mat == 3) ? sb16 : kv16;
    int rowStride = (mat == 1 || mat == 2) ? 1024 : 512;
    int cbase = wcol0 + ((mat == 2) ? 512 : 0);
#pragma unroll
    for (int i = 0; i < 8; i++) {
        int idx = t + i * 256;
        int row2 = idx >> 4;
        int c8 = (idx & 15) * 8;
        int gr = row0 + row2;
        if (gr < NN) {
            unsigned int wb = (unsigned int)(row2 * 64 + (idx & 15) * 4);
            wb ^= ((row2 >> 2) & 7) << 3;
            uint4 v = *(const uint4*)(As + wb * 2);
            *(uint4*)(outp + (size_t)gr * rowStride + cbase + c8) = v;
        }
    }
}

// ---------------- fused attention + beta gate + LN stats ----------------
// ONE BLOCK PER NODE, 4 waves. Every wave covers all 512 channels
// (lane -> (lane>>4)*128 + (lane&15)*8); wave w takes edges beg+w+4k with
// ILP-4 (p, p+4, p+8, p+12 in flight) -> 16 edges in flight per block.
// End-of-node: waves publish (m,s,acc) to LDS; wave 0 merges + epilogue.
__global__ __launch_bounds__(256) void k_attn_beta(
    const unsigned short* __restrict__ qb16,
    const unsigned short* __restrict__ kv16,
    const unsigned short* __restrict__ sb16,
    const float* __restrict__ Wb,
    const int* __restrict__ offs, const int* __restrict__ col,
    unsigned short* __restrict__ gated16, float* __restrict__ stats) {
    int n = blockIdx.x;
    int wave = threadIdx.x >> 6;
    int lane = threadIdx.x & 63;
    int head = lane >> 4;
    const int off = (head << 7) + ((lane & 15) << 3);
    uint4 qq = *(const uint4*)(qb16 + (size_t)n * HCW + off);
    float4 q0 = {lo16(qq.x), hi16(qq.x), lo16(qq.y), hi16(qq.y)};
    float4 q1 = {lo16(qq.z), hi16(qq.z), lo16(qq.w), hi16(qq.w)};
    int beg = offs[n], end = offs[n + 1];
    const float scale = 0.08838834764831845f;  // 1/sqrt(128)

    float m[4], s[4];
    float4 a0[4], a1[4];
#pragma unroll
    for (int i = 0; i < 4; i++) {
        m[i] = -INFINITY; s[i] = 0.f;
        a0[i] = make_float4(0.f, 0.f, 0.f, 0.f);
        a1[i] = make_float4(0.f, 0.f, 0.f, 0.f);
    }

    for (int p = beg + wave; p < end; p += 16) {
        uint4 kk[4], vv[4];
        bool has[4];
#pragma unroll
        for (int i = 0; i < 4; i++) {
            int pi = p + i * 4;
            has[i] = (pi < end);
            int sn = col[has[i] ? pi : p];
            const unsigned short* bp_ = kv16 + ((size_t)sn << 10) + off;
            kk[i] = *(const uint4*)bp_;
            vv[i] = *(const uint4*)(bp_ + 512);
        }
#pragma unroll
        for (int i = 0; i < 4; i++) {
            if (!has[i]) continue;
            float l = red16(dot8(q0, q1, kk[i])) * scale;
            if (l <= m[i] + 8.f) {            // fast path: no rescale
                float w = __expf(l - m[i]);
                s[i] += w;
                a0[i].x += w * lo16(vv[i].x); a0[i].y += w * hi16(vv[i].x);
                a0[i].z += w * lo16(vv[i].y); a0[i].w += w * hi16(vv[i].y);
                a1[i].x += w * lo16(vv[i].z); a1[i].y += w * hi16(vv[i].z);
                a1[i].z += w * lo16(vv[i].w); a1[i].w += w * hi16(vv[i].w);
            } else {                          // rescale (first edge & rare growth)
                float sc = __expf(m[i] - l);  // m=-inf -> 0
                s[i] = s[i] * sc + 1.f;
                a0[i].x = a0[i].x * sc + lo16(vv[i].x); a0[i].y = a0[i].y * sc + hi16(vv[i].x);
                a0[i].z = a0[i].z * sc + lo16(vv[i].y); a0[i].w = a0[i].w * sc + hi16(vv[i].y);
                a1[i].x = a1[i].x * sc + lo16(vv[i].z); a1[i].y = a1[i].y * sc + hi16(vv[i].z);
                a1[i].z = a1[i].z * sc + lo16(vv[i].w); a1[i].w = a1[i].w * sc + hi16(vv[i].w);
                m[i] = l;
            }
        }
    }
    // merge ILP states 1..3 into state 0 (per-lane; same channels)
#pragma unroll
    for (int i = 1; i < 4; i++) {
        float mn = fmaxf(m[0], m[i]);
        float c1 = (s[0] > 0.f) ? __expf(m[0] - mn) : 0.f;
        float c2 = (s[i] > 0.f) ? __expf(m[i] - mn) : 0.f;
        s[0] = s[0] * c1 + s[i] * c2;
        a0[0].x = a0[0].x * c1 + a0[i].x * c2; a0[0].y = a0[0].y * c1 + a0[i].y * c2;
        a0[0].z = a0[0].z * c1 + a0[i].z * c2; a0[0].w = a0[0].w * c1 + a0[i].w * c2;
        a1[0].x = a1[0].x * c1 + a1[i].x * c2; a1[0].y = a1[0].y * c1 + a1[i].y * c2;
        a1[0].z = a1[0].z * c1 + a1[i].z * c2; a1[0].w = a1[0].w * c1 + a1[i].w * c2;
        m[0] = mn;
    }

    // publish wave state to LDS
    __shared__ float lds_acc[4][512];
    __shared__ float lds_m[4][4], lds_s[4][4];
    *(float4*)&lds_acc[wave][off] = a0[0];
    *(float4*)&lds_acc[wave][off + 4] = a1[0];
    if ((lane & 15) == 0) { lds_m[wave][head] = m[0]; lds_s[wave][head] = s[0]; }
    __syncthreads();
    if (wave != 0) return;

    // wave 0: merge the 4 wave-states for its channels
    float M = -INFINITY, S = 0.f;
    float4 A0 = {0.f, 0.f, 0.f, 0.f}, A1 = {0.f, 0.f, 0.f, 0.f};
#pragma unroll
    for (int w = 0; w < 4; w++) {
        float mw = lds_m[w][head];
        float sw = lds_s[w][head];
        float4 b0 = *(const float4*)&lds_acc[w][off];
        float4 b1 = *(const float4*)&lds_acc[w][off + 4];
        float mn = fmaxf(M, mw);
        float c1 = (S > 0.f) ? __expf(M - mn) : 0.f;
        float c2 = (sw > 0.f) ? __expf(mw - mn) : 0.f;
        S = S * c1 + sw * c2;
        A0.x = A0.x * c1 + b0.x * c2; A0.y = A0.y * c1 + b0.y * c2;
        A0.z = A0.z * c1 + b0.z * c2; A0.w = A0.w * c1 + b0.w * c2;
        A1.x = A1.x * c1 + b1.x * c2; A1.y = A1.y * c1 + b1.y * c2;
        A1.z = A1.z * c1 + b1.z * c2; A1.w = A1.w * c1 + b1.w * c2;
        M = mn;
    }
    float inv = (S > 0.f) ? 1.f / S : 0.f;
    float o[8] = {A0.x * inv, A0.y * inv, A0.z * inv, A0.w * inv,
                  A1.x * inv, A1.y * inv, A1.z * inv, A1.w * inv};

    // skip row (8 channels per lane)
    uint4 sku = *(const uint4*)(sb16 + (size_t)n * HCW + off);
    float sk[8] = {lo16(sku.x), hi16(sku.x), lo16(sku.y), hi16(sku.y),
                   lo16(sku.z), hi16(sku.z), lo16(sku.w), hi16(sku.w)};

    // beta gate: partial over this lane's 8 channels, then wave reduce
    float part = 0.f;
#pragma unroll
    for (int j = 0; j < 8; j++) {
        int c = off + j;
        part += o[j] * Wb[c] + sk[j] * Wb[512 + c] + (o[j] - sk[j]) * Wb[1024 + c];
    }
    part = red64(part);
    float beta = 1.f / (1.f + __expf(-part));

    unsigned int gu[4];
    float ls = 0.f, lq = 0.f;
#pragma unroll
    for (int j = 0; j < 4; j++) {
        float gx = beta * sk[2 * j] + (1.f - beta) * o[2 * j];
        float gy = beta * sk[2 * j + 1] + (1.f - beta) * o[2 * j + 1];
        gu[j] = (unsigned int)f2bf(gx) | ((unsigned int)f2bf(gy) << 16);
        float gxr = lo16(gu[j]), gyr = hi16(gu[j]);
        ls += gxr + gyr;
        lq += gxr * gxr + gyr * gyr;
    }
    *(uint4*)(gated16 + (size_t)n * HCW + off) = *(uint4*)gu;

    // LN partial sums -> bucketed atomics (one 64B line per bucket)
    ls = red64(ls);
    lq = red64(lq);
    if (lane == 0) {
        int b = n & (NBUCK - 1);
        atomicAdd(&stats[b * 16], ls);
        atomicAdd(&stats[b * 16 + 1], lq);
    }
}

// ---------------- LN + proj MFMA + residual + relu ----------------
// 64-row tiles, 8 waves (512 thr): wave w computes 16 rows x 64 cols.
__global__ __launch_bounds__(512) void k_proj_mfma(
    const unsigned short* __restrict__ gated16,   // [NN][512] bf16
    const unsigned short* __restrict__ Wpt,       // [128][512] layer slice
    const float* __restrict__ bp,
    const float* __restrict__ lw, const float* __restrict__ lb,
    const float* __restrict__ stats,
    float* __restrict__ h, unsigned short* __restrict__ h_bf) {
    __shared__ unsigned short As[64 * 128];    // 16KB
    __shared__ unsigned short Bs[128 * 128];   // 32KB
    int row0 = blockIdx.x * 64;
    int t = threadIdx.x;
    float ssum = 0.f, sq = 0.f;
#pragma unroll 16
    for (int i = 0; i < NBUCK; i++) { ssum += stats[i * 16]; sq += stats[i * 16 + 1]; }
    const float invM = 1.f / (NN * 512.f);
    float mean = ssum * invM;
    float ms = sq * invM - mean * mean;
    float rstd = 1.f / (sqrtf(fmaxf(ms, 0.f)) + LN_EPS);
    int wave = t >> 6, lane = t & 63;
    int wr = (wave >> 1) * 16, wc = (wave & 1) * 64;
    int lr = lane & 15, lk = lane >> 4;
    f32x4 acc[4] = {};
    for (int kc = 0; kc < 4; kc++) {
        __syncthreads();
#pragma unroll
        for (int i = 0; i < 2; i++) {
            int c = t + i * 512;
            int r = c >> 4, cc = c & 15;
            int gr = row0 + r;
            int gk = kc * 128 + cc * 8;
            unsigned short u[8];
            if (gr < NN) {
                uint4 gv = *(const uint4*)(gated16 + (size_t)gr * 512 + gk);
                float vals[8] = {lo16(gv.x), hi16(gv.x), lo16(gv.y), hi16(gv.y),
                                 lo16(gv.z), hi16(gv.z), lo16(gv.w), hi16(gv.w)};
#pragma unroll
                for (int j = 0; j < 8; j++)
                    u[j] = f2bf((vals[j] - mean) * rstd * lw[gk + j] + lb[gk + j]);
            } else {
#pragma unroll
                for (int j = 0; j < 8; j++) u[j] = 0;
            }
            int sc = (r << 4) | (cc ^ (r & 7));
            *(uint4*)(As + sc * 8) = *(uint4*)u;
        }
#pragma unroll
        for (int i = 0; i < 4; i++) {
            int c = t + i * 512;
            int r = c >> 4, cc = c & 15;
            uint4 v = *(const uint4*)(Wpt + (size_t)r * 512 + kc * 128 + cc * 8);
            int sc = (r << 4) | (cc ^ (r & 7));
            *(uint4*)(Bs + sc * 8) = v;
        }
        __syncthreads();
#pragma unroll
        for (int ks = 0; ks < 4; ks++) {
            bf16x8 a, b[4];
            {
                int r = wr + lr;
                int cc = (ks * 4 + lk) ^ (r & 7);
                a = *(const bf16x8*)(As + (((r << 4) | cc) * 8));
            }
#pragma unroll
            for (int ni = 0; ni < 4; ni++) {
                int r = wc + ni * 16 + lr;
                int cc = (ks * 4 + lk) ^ (r & 7);
                b[ni] = *(const bf16x8*)(Bs + (((r << 4) | cc) * 8));
            }
#pragma unroll
            for (int ni = 0; ni < 4; ni++)
                acc[ni] = __builtin_amdgcn_mfma_f32_16x16x32_bf16(a, b[ni], acc[ni], 0, 0, 0);
        }
    }
#pragma unroll
    for (int ni = 0; ni < 4; ni++) {
        int gc = wc + ni * 16 + lr;  // 0..127
        float bias = bp[gc];
        int gr0 = row0 + wr + 4 * lk;
#pragma unroll
        for (int r = 0; r < 4; r++) {
            int grr = gr0 + r;
            if (grr < NN) {
                float o = acc[ni][r] + bias + h[(size_t)grr * 128 + gc];
                o = fmaxf(o, 0.f);
                h[(size_t)grr * 128 + gc] = o;
                h_bf[(size_t)grr * 128 + gc] = f2bf(o);
            }
        }
    }
}

// ---------------- output projection: wave per node ----------------
__global__ __launch_bounds__(256) void k_out(const float* __restrict__ h,
                                             const float* __restrict__ W,
                                             const float* __restrict__ b,
                                             float* __restrict__ out) {
    int wave = threadIdx.x >> 6, lane = threadIdx.x & 63;
    int n = blockIdx.x * 4 + wave;   // NN % 4 == 0
    float2 hv = *(const float2*)(h + (size_t)n * 128 + lane * 2);
    const float* w0 = W + (lane * 2) * 5;
    float p0 = hv.x * w0[0] + hv.y * w0[5];
    float p1 = hv.x * w0[1] + hv.y * w0[6];
    float p2 = hv.x * w0[2] + hv.y * w0[7];
    float p3 = hv.x * w0[3] + hv.y * w0[8];
    float p4 = hv.x * w0[4] + hv.y * w0[9];
    p0 = red64(p0); p1 = red64(p1); p2 = red64(p2); p3 = red64(p3); p4 = red64(p4);
    if (lane == 0) {
        out[n * 5 + 0] = p0 + b[0];
        out[n * 5 + 1] = p1 + b[1];
        out[n * 5 + 2] = p2 + b[2];
        out[n * 5 + 3] = p3 + b[3];
        out[n * 5 + 4] = p4 + b[4];
    }
}

extern "C" void kernel_launch(void* const* d_in, const int* in_sizes, int n_in,
                              void* d_out, int out_size, void* d_ws, size_t ws_size,
                              hipStream_t stream) {
    const float* x     = (const float*)d_in[0];
    const int* ei      = (const int*)d_in[1];
    const float* W_in  = (const float*)d_in[2];
    const float* b_in  = (const float*)d_in[3];
    const float* W_out = (const float*)d_in[4];
    const float* b_out = (const float*)d_in[5];
    const float* Wq    = (const float*)d_in[6];
    const float* bq    = (const float*)d_in[7];
    const float* Wk    = (const float*)d_in[8];
    const float* bk    = (const float*)d_in[9];
    const float* Wv    = (const float*)d_in[10];
    const float* bv    = (const float*)d_in[11];
    const float* Wsk   = (const float*)d_in[12];
    const float* bsk   = (const float*)d_in[13];
    const float* Wbeta = (const float*)d_in[14];
    const float* ln_w  = (const float*)d_in[15];
    const float* ln_b  = (const float*)d_in[16];
    const float* Wproj = (const float*)d_in[17];
    const float* bproj = (const float*)d_in[18];
    float* out = (float*)d_out;

    // workspace layout
    float* h     = (float*)d_ws;                    // N*128 f32
    float* stats = h + (size_t)NN * 128;            // L*NBUCK*16
    int* offs = (int*)(stats + NLAYERS * NBUCK * 16);  // N+1
    int* cnt  = offs + (NN + 1);
    int* fill = cnt + NN;
    int* col  = fill + NN;                          // E
    unsigned short* h_bf = (unsigned short*)(((uintptr_t)(col + NE) + 15) & ~(uintptr_t)15);
    unsigned short* qb16 = h_bf + (size_t)NN * 128;                // N*512 (also gated)
    unsigned short* sb16 = qb16 + (size_t)NN * 512;                // N*512
    unsigned short* kv16 = sb16 + (size_t)NN * 512;                // N*1024 interleaved K|V
    unsigned short* wt_qkvs = kv16 + (size_t)NN * 1024;            // L*2048*128
    unsigned short* wpt = wt_qkvs + (size_t)NLAYERS * 2048 * 128;  // L*128*512
    unsigned short* gated16 = qb16;  // alias (wave 0 reads q row n before writing)

    const int* src = ei;
    const int* dst = ei + NE;

    k_init<<<(NN + 255) / 256, 256, 0, stream>>>(cnt, fill, stats);
    k_count<<<(NE + 255) / 256, 256, 0, stream>>>(dst, cnt);
    k_scan<<<1, 1024, 0, stream>>>(cnt, offs);
    k_fill<<<(NE + 255) / 256, 256, 0, stream>>>(src, dst, offs, fill, col);
    {
        int tot = NLAYERS * 2048 * 128 + NLAYERS * 128 * 512;
        k_wconv<<<(tot + 255) / 256, 256, 0, stream>>>(Wq, Wk, Wv, Wsk, Wproj, wt_qkvs, wpt);
    }
    k_inproj<<<NN, 128, 0, stream>>>(x, W_in, b_in, h, h_bf);

    for (int l = 0; l < NLAYERS; ++l) {
        const unsigned short* Wt_ = wt_qkvs + (size_t)l * 2048 * 128;
        const unsigned short* Wp_ = wpt + (size_t)l * 128 * 512;
        const float* bq_ = bq + l * 512;
        const float* bk_ = bk + l * 512;
        const float* bv_ = bv + l * 512;
        const float* bs_ = bsk + l * 512;
        const float* Wb_ = Wbeta + (size_t)l * 1536;
        const float* lw_ = ln_w + l * 512;
        const float* lb_ = ln_b + l * 512;
        const float* bp_ = bproj + l * 128;
        float* st = stats + (size_t)l * NBUCK * 16;

        dim3 g1((NN + 127) / 128, 16);
        k_qkvs_mfma<<<g1, 256, 0, stream>>>(h_bf, Wt_, bq_, bk_, bv_, bs_,
                                            qb16, kv16, sb16);
        k_attn_beta<<<NN, 256, 0, stream>>>(qb16, kv16, sb16, Wb_, offs, col, gated16, st);
        k_proj_mfma<<<(NN + 63) / 64, 512, 0, stream>>>(gated16, Wp_, bp_, lw_, lb_, st, h, h_bf);
    }
    k_out<<<NN / 4, 256, 0, stream>>>(h, W_out, b_out, out);
}